// Round 8
// baseline (69.147 us; speedup 1.0000x reference)
//
#include <hip/hip_runtime.h>
#include <hip/hip_bf16.h>
#include <math.h>

#define HW   4096
#define NC   64
#define NB   2
#define NHD  4
#define DH   16
#define NBH  (NB*NHD)

typedef __attribute__((ext_vector_type(4))) float f32x4;
typedef __attribute__((ext_vector_type(8))) short bf16x8;
typedef __attribute__((ext_vector_type(2))) unsigned int uint2v;

#define QSCALE 0.36067376022224087f   // 0.25 * log2(e)

static __device__ __forceinline__ unsigned short bf16_bits(float f) {
    union { __hip_bfloat16 h; unsigned short u; } cv;
    cv.h = __float2bfloat16(f);
    return cv.u;
}
static __device__ __forceinline__ float bits_to_f(unsigned short b) {
    return __uint_as_float(((unsigned int)b) << 16);
}
static __device__ __forceinline__ unsigned int cvt_pk_bf16(float lo, float hi) {
    unsigned int r;
    asm("v_cvt_pk_bf16_f32 %0, %1, %2" : "=v"(r) : "v"(lo), "v"(hi));
    return r;
}

// ---------------------------------------------------------------------------
// Kernel A: qkv + illu 1x1 convs. 1024 blocks x 256 thr (4 balanced waves:
// q / k_qkv / illu / v), 8 pixels/block. K = k_qkv + k_illu summed via LDS.
// Q (pre-scaled 0.25*log2e) and K DOUBLE-BF16 [bh][p][32] (hi 0-15, lo 16-31).
// V single bf16 transposed Vt [bh][d][key]. Coalesced 16B-chunk writes.
// ---------------------------------------------------------------------------
__global__ __launch_bounds__(256) void qkv_kernel(
    const float* __restrict__ x, const float* __restrict__ illu,
    const float* __restrict__ qkv_w, const float* __restrict__ qkv_b,
    const float* __restrict__ illu_w, const float* __restrict__ illu_b,
    ushort* __restrict__ Qx, ushort* __restrict__ Kx, ushort* __restrict__ Vt)
{
    const int PIX = 8;
    __shared__ float  xs[PIX][NC];
    __shared__ float  fs[PIX][NC];
    __shared__ float  kp1[PIX][NC];
    __shared__ float  kp2[PIX][NC];
    __shared__ ushort qs[NHD][PIX][32];
    __shared__ ushort ks[NHD][PIX][32];
    __shared__ ushort vs[NC][PIX];
    int blk = blockIdx.x;                   // 1024
    int b   = blk >> 9;
    int p0  = (blk & 511) * PIX;
    int tid = threadIdx.x;

    for (int idx = tid; idx < PIX*NC; idx += 256) {
        int ch = idx >> 3;
        int pp = idx & 7;
        xs[pp][ch] = x   [(b*NC + ch)*HW + p0 + pp];
        fs[pp][ch] = illu[(b*NC + ch)*HW + p0 + pp];
    }

    int role = tid >> 6;                    // 0=q 1=k_qkv 2=illu 3=v
    int co   = tid & 63;
    int head = co >> 4;
    int dd   = co & 15;

    const float* wrow = (role == 0) ? qkv_w  + (size_t)co*NC
                      : (role == 1) ? qkv_w  + (size_t)(64 + co)*NC
                      : (role == 2) ? illu_w + (size_t)co*NC
                      :               qkv_w  + (size_t)(128 + co)*NC;
    float bias = (role == 0) ? qkv_b[co]
               : (role == 1) ? qkv_b[64 + co]
               : (role == 2) ? illu_b[co]
               :               qkv_b[128 + co];

    float wq[NC];
    #pragma unroll
    for (int c4 = 0; c4 < NC/4; c4++) {
        float4 w = ((const float4*)wrow)[c4];
        wq[4*c4+0] = w.x; wq[4*c4+1] = w.y; wq[4*c4+2] = w.z; wq[4*c4+3] = w.w;
    }
    __syncthreads();

    const float* srcBase = (role == 2) ? &fs[0][0] : &xs[0][0];
    #pragma unroll
    for (int pp = 0; pp < PIX; pp++) {
        float a0 = 0.f, a1 = 0.f, a2 = 0.f, a3 = 0.f;
        const float4* sp = (const float4*)(srcBase + pp*NC);
        #pragma unroll
        for (int c4 = 0; c4 < NC/4; c4++) {
            float4 xv = sp[c4];
            a0 = fmaf(wq[4*c4+0], xv.x, a0);
            a1 = fmaf(wq[4*c4+1], xv.y, a1);
            a2 = fmaf(wq[4*c4+2], xv.z, a2);
            a3 = fmaf(wq[4*c4+3], xv.w, a3);
        }
        float acc = bias + ((a0 + a1) + (a2 + a3));
        if (role == 0) {
            float v = acc * QSCALE;
            unsigned short hb = bf16_bits(v);
            qs[head][pp][dd]      = hb;
            qs[head][pp][16 + dd] = bf16_bits(v - bits_to_f(hb));
        } else if (role == 1) {
            kp1[pp][co] = acc;
        } else if (role == 2) {
            kp2[pp][co] = acc;
        } else {
            vs[co][pp] = bf16_bits(acc);
        }
    }
    __syncthreads();
    if (role == 1) {
        #pragma unroll
        for (int pp = 0; pp < PIX; pp++) {
            float a = kp1[pp][co] + kp2[pp][co];
            unsigned short hb = bf16_bits(a);
            ks[head][pp][dd]      = hb;
            ks[head][pp][16 + dd] = bf16_bits(a - bits_to_f(hb));
        }
    }
    __syncthreads();

    const ushort* qf = &qs[0][0][0];
    const ushort* kf = &ks[0][0][0];
    for (int u = tid; u < 320; u += 256) {
        if (u < 128) {
            int h = u >> 5, inner = u & 31;
            *(bf16x8*)(Qx + ((size_t)(b*NHD + h))*HW*32 + (size_t)p0*32 + inner*8)
                = *(const bf16x8*)(qf + h*PIX*32 + inner*8);
        } else if (u < 256) {
            int h = (u - 128) >> 5, inner = (u - 128) & 31;
            *(bf16x8*)(Kx + ((size_t)(b*NHD + h))*HW*32 + (size_t)p0*32 + inner*8)
                = *(const bf16x8*)(kf + h*PIX*32 + inner*8);
        } else {
            int cc = u - 256;
            *(bf16x8*)(Vt + ((size_t)(b*NC + cc))*HW + p0)
                = *(const bf16x8*)(&vs[cc][0]);
        }
    }
}

// ---------------------------------------------------------------------------
// Kernel B: MFMA flash attention, 4-way in-block split-K.
// 512 blocks x 1024 thr = 16 waves: wave w -> split s=w>>2 (keys s*1024..),
// q-group qg=w&3 (rows q0+qg*16..). KT=64. Per-split double-buffered K/V;
// ONE barrier per tile; global->reg prefetch overlaps compute.
// Swapped QK^T: mfma(K,Q), K double-bf16 (hi|lo), B1=[Qhi|Qhi], B2=[Qlo|Qlo].
// P single bf16 via v_cvt_pk. No-max softmax. Merge buffer REUSES Ks LDS.
// O written as [b][p][64].
// ---------------------------------------------------------------------------
#define KT     64
#define SPL    4
#define KPS    1024          // keys per split
#define NTS    (KPS/KT)      // 16 tiles per split

__global__ __launch_bounds__(1024) void attn_kernel(
    const ushort* __restrict__ Qx, const ushort* __restrict__ Kx,
    const ushort* __restrict__ Vt, float* __restrict__ O)
{
    __shared__ alignas(16) ushort Ks[SPL][2][64*32];   // 32KB
    __shared__ alignas(16) ushort Vs[SPL][2][16*68];   // 17.4KB

    int blk  = blockIdx.x;               // 512
    int bh   = blk >> 6;
    int q0   = (blk & 63) * 64;
    int tid  = threadIdx.x;              // 0..1023
    int w    = tid >> 6;                 // wave 0..15
    int s    = w >> 2;                   // split 0..3
    int qg   = w & 3;                    // q-group 0..3
    int lane = tid & 63;
    int g    = lane >> 4;
    int qc   = lane & 15;

    const ushort* Qb = Qx + (size_t)bh*HW*32;
    const ushort* Kb = Kx + (size_t)bh*HW*32 + (size_t)s*KPS*32;
    const ushort* Vb = Vt + (size_t)bh*DH*HW;

    int qrow = q0 + qg*16 + qc;
    bf16x8 qhi = *(const bf16x8*)(Qb + (size_t)qrow*32 +      8*(g&1));
    bf16x8 qlo = *(const bf16x8*)(Qb + (size_t)qrow*32 + 16 + 8*(g&1));

    f32x4 zero4 = {0.f, 0.f, 0.f, 0.f};
    f32x4 oacc  = {0.f, 0.f, 0.f, 0.f};
    float l = 0.f;

    // compute-side lane-constant addressing (krow = kb*16+qc, kb 0..3:
    // (krow>>2)&3 == (qc>>2)&3 since 4*kb ≡ 0 mod 4)
    int mconst = (qc & 3) ^ ((qc >> 2) & 3);
    const int koff = qc*32 + ((g ^ mconst)*8);
    const int voff = qc*68 + 4*g;

    // staging-side: 256 thr per split; K tile = 256 chunks, V tile = 128
    int gt = tid & 255;
    int r0 = gt >> 2, h0 = gt & 3;
    int s0 = (h0 ^ ((r0 & 3) ^ ((r0 >> 2) & 3))) * 8;
    int vd = gt >> 3, vseg = gt & 7;     // valid when gt < 128
    bool doV = (gt < 128);

    // prologue: tile 0 of this split -> regs -> buf0
    bf16x8 gk = *(const bf16x8*)(Kb + (size_t)r0*32 + 8*h0);
    bf16x8 gv;
    if (doV) gv = *(const bf16x8*)(Vb + (size_t)vd*HW + s*KPS + vseg*8);
    *(bf16x8*)(&Ks[s][0][0] + r0*32 + s0) = gk;
    if (doV) *(bf16x8*)(&Vs[s][0][0] + vd*68 + vseg*8) = gv;

    for (int t = 0; t < NTS; ++t) {
        __syncthreads();
        if (t + 1 < NTS) {
            int kt = (t + 1) * KT;
            gk = *(const bf16x8*)(Kb + (size_t)(kt + r0)*32 + 8*h0);
            if (doV) gv = *(const bf16x8*)(Vb + (size_t)vd*HW + s*KPS + kt + vseg*8);
        }

        const ushort* kr = &Ks[s][t & 1][0] + koff;
        const ushort* vr = &Vs[s][t & 1][0] + voff;
        unsigned int pe0 = 0, pe1 = 0;
        #pragma unroll
        for (int kb = 0; kb < 4; ++kb) {
            bf16x8 kfrag = *(const bf16x8*)(kr + kb*512);
            f32x4 sS = __builtin_amdgcn_mfma_f32_16x16x32_bf16(kfrag, qhi, zero4, 0, 0, 0);
            sS = __builtin_amdgcn_mfma_f32_16x16x32_bf16(kfrag, qlo, sS, 0, 0, 0);
            float p0 = __builtin_amdgcn_exp2f(sS.x);
            float p1 = __builtin_amdgcn_exp2f(sS.y);
            float p2 = __builtin_amdgcn_exp2f(sS.z);
            float p3 = __builtin_amdgcn_exp2f(sS.w);
            l += (p0 + p1) + (p2 + p3);
            unsigned int plo = cvt_pk_bf16(p0, p1);
            unsigned int phi = cvt_pk_bf16(p2, p3);
            if ((kb & 1) == 0) { pe0 = plo; pe1 = phi; }
            else {
                uint2v vE = *(const uint2v*)(vr + (kb-1)*16);
                uint2v vO = *(const uint2v*)(vr + kb*16);
                union { unsigned int u[4]; bf16x8 h; } pa, vb;
                pa.u[0] = pe0;  pa.u[1] = pe1;  pa.u[2] = plo;  pa.u[3] = phi;
                vb.u[0] = vE.x; vb.u[1] = vE.y; vb.u[2] = vO.x; vb.u[3] = vO.y;
                oacc = __builtin_amdgcn_mfma_f32_16x16x32_bf16(pa.h, vb.h, oacc, 0, 0, 0);
            }
        }

        if (t + 1 < NTS) {
            int nb = (t + 1) & 1;
            *(bf16x8*)(&Ks[s][nb][0] + r0*32 + s0) = gk;
            if (doV) *(bf16x8*)(&Vs[s][nb][0] + vd*68 + vseg*8) = gv;
        }
    }

    // split-local denominator reduce
    l += __shfl_xor(l, 16);
    l += __shfl_xor(l, 32);

    // merge splits 1..3 -> split 0, reusing Ks LDS (staging is dead now)
    __syncthreads();
    float* mrgF = (float*)&Ks[0][0][0];   // [3][4][64][5] floats = 15360 B
    if (s > 0) {
        float* m = mrgF + ((((s-1)*4 + qg)*64 + lane)*5);
        m[0] = oacc.x; m[1] = oacc.y; m[2] = oacc.z; m[3] = oacc.w; m[4] = l;
    }
    __syncthreads();
    if (s == 0) {
        #pragma unroll
        for (int sp = 0; sp < 3; ++sp) {
            const float* m = mrgF + (((sp*4 + qg)*64 + lane)*5);
            oacc.x += m[0]; oacc.y += m[1]; oacc.z += m[2]; oacc.w += m[3];
            l += m[4];
        }
        int b = bh >> 2, h = bh & 3;
        float* Ob = O + ((size_t)b*HW + q0 + qg*16)*NC + h*DH;
        #pragma unroll
        for (int r = 0; r < 4; ++r) {
            float lr = __shfl(l, 4*g + r);
            float ov = (r==0? oacc.x : r==1? oacc.y : r==2? oacc.z : oacc.w);
            Ob[(4*g + r)*NC + qc] = ov / lr;
        }
    }
}

// ---------------------------------------------------------------------------
// Kernel C: proj 1x1 conv + transpose. 2048 blocks x 256 thr, 4 pixels each.
// O is [b][p][64] -> fully contiguous input loads.
// ---------------------------------------------------------------------------
__global__ __launch_bounds__(256) void proj_kernel(
    const float* __restrict__ O, const float* __restrict__ proj_w,
    const float* __restrict__ proj_b, float* __restrict__ y)
{
    const int PIX = 4;
    __shared__ float os[PIX][NC];        // 1KB
    __shared__ float ys[NC][PIX+1];
    int blk = blockIdx.x;                // 2048
    int b   = blk >> 10;
    int p0  = (blk & 1023) * PIX;
    int tid = threadIdx.x;
    int c   = tid & 63;
    int pg  = tid >> 6;                  // 0..3 -> pixel pg

    if (tid < PIX*NC/4) {                // 64 float4 contiguous loads
        int pp = tid >> 4, c4 = tid & 15;
        ((float4*)os[pp])[c4] = ((const float4*)(O + ((size_t)(b*HW + p0 + pp))*NC))[c4];
    }
    float wv[NC];
    #pragma unroll
    for (int c4 = 0; c4 < NC/4; c4++) {
        float4 t = ((const float4*)(proj_w + (size_t)c*NC))[c4];
        wv[4*c4+0] = t.x; wv[4*c4+1] = t.y; wv[4*c4+2] = t.z; wv[4*c4+3] = t.w;
    }
    float bias = proj_b[c];
    __syncthreads();

    {
        int pi = pg;
        float a0 = 0.f, a1 = 0.f, a2 = 0.f, a3 = 0.f;
        #pragma unroll
        for (int c4 = 0; c4 < NC/4; c4++) {
            float4 ov = ((const float4*)os[pi])[c4];
            a0 = fmaf(wv[4*c4+0], ov.x, a0);
            a1 = fmaf(wv[4*c4+1], ov.y, a1);
            a2 = fmaf(wv[4*c4+2], ov.z, a2);
            a3 = fmaf(wv[4*c4+3], ov.w, a3);
        }
        ys[c][pi] = bias + ((a0 + a1) + (a2 + a3));
    }
    __syncthreads();
    if (tid < PIX*NC) {
        int cc = tid >> 2;
        int i  = tid & 3;
        y[(size_t)(b*NC + cc)*HW + p0 + i] = ys[cc][i];
    }
}

// ---------------------------------------------------------------------------
extern "C" void kernel_launch(void* const* d_in, const int* in_sizes, int n_in,
                              void* d_out, int out_size, void* d_ws, size_t ws_size,
                              hipStream_t stream)
{
    const float* x      = (const float*)d_in[0];
    const float* illu   = (const float*)d_in[1];
    const float* qkv_w  = (const float*)d_in[2];
    const float* qkv_b  = (const float*)d_in[3];
    const float* illu_w = (const float*)d_in[4];
    const float* illu_b = (const float*)d_in[5];
    const float* proj_w = (const float*)d_in[6];
    const float* proj_b = (const float*)d_in[7];
    float* out = (float*)d_out;

    ushort* Qx = (ushort*)d_ws;                     // 2MB (hi|lo)
    ushort* Kx = Qx + (size_t)NBH*HW*32;            // 2MB (hi|lo)
    ushort* Vt = Kx + (size_t)NBH*HW*32;            // 1MB [bh][d][key]
    float*  O  = (float*)(Vt + (size_t)NBH*HW*DH);  // 2MB fp32 [b][p][64]

    hipLaunchKernelGGL(qkv_kernel, dim3(1024), dim3(256), 0, stream,
                       x, illu, qkv_w, qkv_b, illu_w, illu_b, Qx, Kx, Vt);
    hipLaunchKernelGGL(attn_kernel, dim3(512), dim3(1024), 0, stream,
                       Qx, Kx, Vt, O);
    hipLaunchKernelGGL(proj_kernel, dim3(2048), dim3(256), 0, stream,
                       O, proj_w, proj_b, out);
}

// Round 10
// 61.747 us; speedup vs baseline: 1.1198x; 1.1198x over previous
//
#include <hip/hip_runtime.h>
#include <hip/hip_bf16.h>
#include <math.h>

#define HW   4096
#define NC   64
#define NB   2
#define NHD  4
#define DH   16
#define NBH  (NB*NHD)

typedef __attribute__((ext_vector_type(4))) float f32x4;
typedef __attribute__((ext_vector_type(8))) short bf16x8;
typedef __attribute__((ext_vector_type(2))) unsigned int uint2v;

#define QSCALE 0.36067376022224087f   // 0.25 * log2(e)

static __device__ __forceinline__ unsigned short bf16_bits(float f) {
    union { __hip_bfloat16 h; unsigned short u; } cv;
    cv.h = __float2bfloat16(f);
    return cv.u;
}
static __device__ __forceinline__ float bits_to_f(unsigned short b) {
    return __uint_as_float(((unsigned int)b) << 16);
}
static __device__ __forceinline__ unsigned int cvt_pk_bf16(float lo, float hi) {
    unsigned int r;
    asm("v_cvt_pk_bf16_f32 %0, %1, %2" : "=v"(r) : "v"(lo), "v"(hi));
    return r;
}

// ---------------------------------------------------------------------------
// Kernel A: qkv + illu 1x1 convs. 1024 blocks x 256 thr (4 balanced waves:
// q / k_qkv / illu / v), 8 pixels/block. K = k_qkv + k_illu summed via LDS.
// Q (pre-scaled 0.25*log2e) and K DOUBLE-BF16 [bh][p][32] (hi 0-15, lo 16-31).
// V single bf16 transposed Vt [bh][d][key]. Coalesced 16B-chunk writes.
// Input staging float4-coalesced (values identical to scalar version).
// ---------------------------------------------------------------------------
__global__ __launch_bounds__(256) void qkv_kernel(
    const float* __restrict__ x, const float* __restrict__ illu,
    const float* __restrict__ qkv_w, const float* __restrict__ qkv_b,
    const float* __restrict__ illu_w, const float* __restrict__ illu_b,
    ushort* __restrict__ Qx, ushort* __restrict__ Kx, ushort* __restrict__ Vt)
{
    const int PIX = 8;
    __shared__ float  xs[PIX][NC];
    __shared__ float  fs[PIX][NC];
    __shared__ float  kp1[PIX][NC];
    __shared__ float  kp2[PIX][NC];
    __shared__ ushort qs[NHD][PIX][32];
    __shared__ ushort ks[NHD][PIX][32];
    __shared__ ushort vs[NC][PIX];
    int blk = blockIdx.x;                   // 1024
    int b   = blk >> 9;
    int p0  = (blk & 511) * PIX;
    int tid = threadIdx.x;

    if (tid < 128) {                        // x: 64 ch x 2 float4
        int ch = tid >> 1, j = tid & 1;
        float4 v = *(const float4*)(x + (size_t)(b*NC + ch)*HW + p0 + 4*j);
        xs[4*j+0][ch] = v.x; xs[4*j+1][ch] = v.y;
        xs[4*j+2][ch] = v.z; xs[4*j+3][ch] = v.w;
    } else {                                // illu: 64 ch x 2 float4
        int t2 = tid - 128;
        int ch = t2 >> 1, j = t2 & 1;
        float4 v = *(const float4*)(illu + (size_t)(b*NC + ch)*HW + p0 + 4*j);
        fs[4*j+0][ch] = v.x; fs[4*j+1][ch] = v.y;
        fs[4*j+2][ch] = v.z; fs[4*j+3][ch] = v.w;
    }

    int role = tid >> 6;                    // 0=q 1=k_qkv 2=illu 3=v
    int co   = tid & 63;
    int head = co >> 4;
    int dd   = co & 15;

    const float* wrow = (role == 0) ? qkv_w  + (size_t)co*NC
                      : (role == 1) ? qkv_w  + (size_t)(64 + co)*NC
                      : (role == 2) ? illu_w + (size_t)co*NC
                      :               qkv_w  + (size_t)(128 + co)*NC;
    float bias = (role == 0) ? qkv_b[co]
               : (role == 1) ? qkv_b[64 + co]
               : (role == 2) ? illu_b[co]
               :               qkv_b[128 + co];

    float wq[NC];
    #pragma unroll
    for (int c4 = 0; c4 < NC/4; c4++) {
        float4 w = ((const float4*)wrow)[c4];
        wq[4*c4+0] = w.x; wq[4*c4+1] = w.y; wq[4*c4+2] = w.z; wq[4*c4+3] = w.w;
    }
    __syncthreads();

    const float* srcBase = (role == 2) ? &fs[0][0] : &xs[0][0];
    #pragma unroll
    for (int pp = 0; pp < PIX; pp++) {
        float a0 = 0.f, a1 = 0.f, a2 = 0.f, a3 = 0.f;
        const float4* sp = (const float4*)(srcBase + pp*NC);
        #pragma unroll
        for (int c4 = 0; c4 < NC/4; c4++) {
            float4 xv = sp[c4];
            a0 = fmaf(wq[4*c4+0], xv.x, a0);
            a1 = fmaf(wq[4*c4+1], xv.y, a1);
            a2 = fmaf(wq[4*c4+2], xv.z, a2);
            a3 = fmaf(wq[4*c4+3], xv.w, a3);
        }
        float acc = bias + ((a0 + a1) + (a2 + a3));
        if (role == 0) {
            float v = acc * QSCALE;
            unsigned short hb = bf16_bits(v);
            qs[head][pp][dd]      = hb;
            qs[head][pp][16 + dd] = bf16_bits(v - bits_to_f(hb));
        } else if (role == 1) {
            kp1[pp][co] = acc;
        } else if (role == 2) {
            kp2[pp][co] = acc;
        } else {
            vs[co][pp] = bf16_bits(acc);
        }
    }
    __syncthreads();
    if (role == 1) {
        #pragma unroll
        for (int pp = 0; pp < PIX; pp++) {
            float a = kp1[pp][co] + kp2[pp][co];
            unsigned short hb = bf16_bits(a);
            ks[head][pp][dd]      = hb;
            ks[head][pp][16 + dd] = bf16_bits(a - bits_to_f(hb));
        }
    }
    __syncthreads();

    const ushort* qf = &qs[0][0][0];
    const ushort* kf = &ks[0][0][0];
    for (int u = tid; u < 320; u += 256) {
        if (u < 128) {
            int h = u >> 5, inner = u & 31;
            *(bf16x8*)(Qx + ((size_t)(b*NHD + h))*HW*32 + (size_t)p0*32 + inner*8)
                = *(const bf16x8*)(qf + h*PIX*32 + inner*8);
        } else if (u < 256) {
            int h = (u - 128) >> 5, inner = (u - 128) & 31;
            *(bf16x8*)(Kx + ((size_t)(b*NHD + h))*HW*32 + (size_t)p0*32 + inner*8)
                = *(const bf16x8*)(kf + h*PIX*32 + inner*8);
        } else {
            int cc = u - 256;
            *(bf16x8*)(Vt + ((size_t)(b*NC + cc))*HW + p0)
                = *(const bf16x8*)(&vs[cc][0]);
        }
    }
}

// ---------------------------------------------------------------------------
// Kernel B: MFMA flash attention, 2-way in-block split-K (round-7 structure,
// bit-identical math). 512 blocks x 512 thr = 8 waves: wave w -> split
// s=w>>2 (keys s*2048..), q-group qg=w&3. KT=128, per-split double-buffered
// K AND V in LDS; ONE barrier per tile; global->reg prefetch overlaps compute.
// Swapped QK^T: mfma(K,Q), K double-bf16 (hi|lo), B1=[Qhi|Qhi], B2=[Qlo|Qlo].
// P single bf16 via v_cvt_pk. No-max softmax. Merge buffer REUSES Ks[0][0]
// (barrier-ordered; saves 5KB -> 49.4KB LDS -> 3 blocks/CU, 6 waves/SIMD).
// O written as [b][p][64].
// ---------------------------------------------------------------------------
#define KT   128
#define KPS  2048          // keys per split
#define NTS  (KPS/KT)      // 16 tiles per split

__global__ __launch_bounds__(512) void attn_kernel(
    const ushort* __restrict__ Qx, const ushort* __restrict__ Kx,
    const ushort* __restrict__ Vt, float* __restrict__ O)
{
    __shared__ alignas(16) ushort Ks[2][2][128*32];  // 32KB  [split][buf]
    __shared__ alignas(16) ushort Vs[2][2][16*136];  // 17.4KB

    int blk  = blockIdx.x;               // 512
    int bh   = blk >> 6;
    int q0   = (blk & 63) * 64;
    int tid  = threadIdx.x;              // 0..511
    int w    = tid >> 6;                 // wave 0..7
    int s    = w >> 2;                   // key split 0..1
    int qg   = w & 3;                    // q-group 0..3
    int lane = tid & 63;
    int g    = lane >> 4;                // lane group 0..3
    int qc   = lane & 15;                // query col / A-row / V d-col

    const ushort* Qb = Qx + (size_t)bh*HW*32;
    const ushort* Kb = Kx + (size_t)bh*HW*32 + (size_t)s*KPS*32;
    const ushort* Vb = Vt + (size_t)bh*DH*HW;  // key offset added per access

    int qrow = q0 + qg*16 + qc;
    bf16x8 qhi = *(const bf16x8*)(Qb + (size_t)qrow*32 +      8*(g&1));
    bf16x8 qlo = *(const bf16x8*)(Qb + (size_t)qrow*32 + 16 + 8*(g&1));

    f32x4 zero4 = {0.f, 0.f, 0.f, 0.f};
    f32x4 oacc  = {0.f, 0.f, 0.f, 0.f};
    f32x4 lacc  = {0.f, 0.f, 0.f, 0.f};

    // compute-side lane-constant addressing
    int mconst = (qc & 3) ^ ((qc >> 2) & 3);
    const int koff = qc*32 + ((g ^ mconst)*8);
    const int voff = qc*136 + 4*g;

    // staging-side thread-constant addressing (group = 256 thr of this split)
    int gt = tid & 255;
    int f0 = gt,        r0 = f0 >> 2, h0 = f0 & 3;
    int f1 = gt + 256,  r1 = f1 >> 2, h1 = f1 & 3;
    int s0 = (h0 ^ ((r0 & 3) ^ ((r0 >> 2) & 3))) * 8;
    int s1 = (h1 ^ ((r1 & 3) ^ ((r1 >> 2) & 3))) * 8;
    int vd = gt >> 4, vseg = gt & 15;

    // prologue: tile 0 of this split -> regs -> buf0
    bf16x8 gk0 = *(const bf16x8*)(Kb + (size_t)r0*32 + 8*h0);
    bf16x8 gk1 = *(const bf16x8*)(Kb + (size_t)r1*32 + 8*h1);
    bf16x8 gv  = *(const bf16x8*)(Vb + (size_t)vd*HW + s*KPS + vseg*8);
    *(bf16x8*)(&Ks[s][0][0] + r0*32 + s0) = gk0;
    *(bf16x8*)(&Ks[s][0][0] + r1*32 + s1) = gk1;
    *(bf16x8*)(&Vs[s][0][0] + vd*136 + vseg*8) = gv;

    for (int t = 0; t < NTS; ++t) {
        __syncthreads();
        if (t + 1 < NTS) {               // prefetch tile t+1 into regs
            int kt = (t + 1) * KT;
            gk0 = *(const bf16x8*)(Kb + (size_t)(kt + r0)*32 + 8*h0);
            gk1 = *(const bf16x8*)(Kb + (size_t)(kt + r1)*32 + 8*h1);
            gv  = *(const bf16x8*)(Vb + (size_t)vd*HW + s*KPS + kt + vseg*8);
        }

        const ushort* kr = &Ks[s][t & 1][0] + koff;
        const ushort* vr = &Vs[s][t & 1][0] + voff;
        unsigned int pe0 = 0, pe1 = 0;
        #pragma unroll
        for (int kb = 0; kb < 8; ++kb) {
            bf16x8 kfrag = *(const bf16x8*)(kr + kb*512);
            f32x4 sS = __builtin_amdgcn_mfma_f32_16x16x32_bf16(kfrag, qhi, zero4, 0, 0, 0);
            sS = __builtin_amdgcn_mfma_f32_16x16x32_bf16(kfrag, qlo, sS, 0, 0, 0);
            float p0 = __builtin_amdgcn_exp2f(sS.x);
            float p1 = __builtin_amdgcn_exp2f(sS.y);
            float p2 = __builtin_amdgcn_exp2f(sS.z);
            float p3 = __builtin_amdgcn_exp2f(sS.w);
            lacc.x += p0; lacc.y += p1; lacc.z += p2; lacc.w += p3;
            unsigned int plo = cvt_pk_bf16(p0, p1);
            unsigned int phi = cvt_pk_bf16(p2, p3);
            if ((kb & 1) == 0) { pe0 = plo; pe1 = phi; }
            else {
                uint2v vE = *(const uint2v*)(vr + (kb-1)*16);
                uint2v vO = *(const uint2v*)(vr + kb*16);
                union { unsigned int u[4]; bf16x8 h; } pa, vb;
                pa.u[0] = pe0;  pa.u[1] = pe1;  pa.u[2] = plo;  pa.u[3] = phi;
                vb.u[0] = vE.x; vb.u[1] = vE.y; vb.u[2] = vO.x; vb.u[3] = vO.y;
                oacc = __builtin_amdgcn_mfma_f32_16x16x32_bf16(pa.h, vb.h, oacc, 0, 0, 0);
            }
        }

        if (t + 1 < NTS) {               // write prefetched regs -> other buf
            int nb = (t + 1) & 1;
            *(bf16x8*)(&Ks[s][nb][0] + r0*32 + s0) = gk0;
            *(bf16x8*)(&Ks[s][nb][0] + r1*32 + s1) = gk1;
            *(bf16x8*)(&Vs[s][nb][0] + vd*136 + vseg*8) = gv;
        }
    }

    // split-local denominator reduce
    float l = (lacc.x + lacc.y) + (lacc.z + lacc.w);
    l += __shfl_xor(l, 16);
    l += __shfl_xor(l, 32);

    // merge split 1 -> split 0, reusing Ks[0][0] (staging dead; barrier-ordered)
    __syncthreads();
    float* mrgF = (float*)&Ks[0][0][0];  // [4][64][5] floats = 5120 B
    if (s == 1) {
        float* m = mrgF + ((qg*64 + lane)*5);
        m[0] = oacc.x; m[1] = oacc.y; m[2] = oacc.z; m[3] = oacc.w; m[4] = l;
    }
    __syncthreads();
    if (s == 0) {
        const float* m = mrgF + ((qg*64 + lane)*5);
        oacc.x += m[0]; oacc.y += m[1]; oacc.z += m[2]; oacc.w += m[3];
        l += m[4];
        int b = bh >> 2, h = bh & 3;
        float* Ob = O + ((size_t)b*HW + q0 + qg*16)*NC + h*DH;
        #pragma unroll
        for (int r = 0; r < 4; ++r) {
            float lr = __shfl(l, 4*g + r);
            float ov = (r==0? oacc.x : r==1? oacc.y : r==2? oacc.z : oacc.w);
            Ob[(4*g + r)*NC + qc] = ov / lr;
        }
    }
}

// ---------------------------------------------------------------------------
// Kernel C: proj 1x1 conv + transpose. 1024 blocks x 256 thr, 8 pixels each.
// O is [b][p][64] -> fully contiguous input loads.
// ---------------------------------------------------------------------------
__global__ __launch_bounds__(256) void proj_kernel(
    const float* __restrict__ O, const float* __restrict__ proj_w,
    const float* __restrict__ proj_b, float* __restrict__ y)
{
    const int PIX = 8;
    __shared__ float os[PIX][NC];        // 2KB
    __shared__ float ys[NC][PIX+1];
    int blk = blockIdx.x;                // 1024
    int b   = blk >> 9;
    int p0  = (blk & 511) * PIX;
    int tid = threadIdx.x;
    int c   = tid & 63;
    int pg  = tid >> 6;                  // 0..3 -> pixels pg*2+u

    if (tid < PIX*NC/4) {                // 128 float4 contiguous loads
        int pp = tid >> 4, c4 = tid & 15;
        ((float4*)os[pp])[c4] = ((const float4*)(O + ((size_t)(b*HW + p0 + pp))*NC))[c4];
    }
    float wv[NC];
    #pragma unroll
    for (int c4 = 0; c4 < NC/4; c4++) {
        float4 t = ((const float4*)(proj_w + (size_t)c*NC))[c4];
        wv[4*c4+0] = t.x; wv[4*c4+1] = t.y; wv[4*c4+2] = t.z; wv[4*c4+3] = t.w;
    }
    float bias = proj_b[c];
    __syncthreads();

    #pragma unroll
    for (int u = 0; u < 2; ++u) {
        int pi = pg*2 + u;
        float a0 = 0.f, a1 = 0.f, a2 = 0.f, a3 = 0.f;
        #pragma unroll
        for (int c4 = 0; c4 < NC/4; c4++) {
            float4 ov = ((const float4*)os[pi])[c4];
            a0 = fmaf(wv[4*c4+0], ov.x, a0);
            a1 = fmaf(wv[4*c4+1], ov.y, a1);
            a2 = fmaf(wv[4*c4+2], ov.z, a2);
            a3 = fmaf(wv[4*c4+3], ov.w, a3);
        }
        ys[c][pi] = bias + ((a0 + a1) + (a2 + a3));
    }
    __syncthreads();
    for (int idx = tid; idx < PIX*NC; idx += 256) {
        int cc = idx >> 3;
        int i  = idx & 7;
        y[(size_t)(b*NC + cc)*HW + p0 + i] = ys[cc][i];
    }
}

// ---------------------------------------------------------------------------
extern "C" void kernel_launch(void* const* d_in, const int* in_sizes, int n_in,
                              void* d_out, int out_size, void* d_ws, size_t ws_size,
                              hipStream_t stream)
{
    const float* x      = (const float*)d_in[0];
    const float* illu   = (const float*)d_in[1];
    const float* qkv_w  = (const float*)d_in[2];
    const float* qkv_b  = (const float*)d_in[3];
    const float* illu_w = (const float*)d_in[4];
    const float* illu_b = (const float*)d_in[5];
    const float* proj_w = (const float*)d_in[6];
    const float* proj_b = (const float*)d_in[7];
    float* out = (float*)d_out;

    ushort* Qx = (ushort*)d_ws;                     // 2MB (hi|lo)
    ushort* Kx = Qx + (size_t)NBH*HW*32;            // 2MB (hi|lo)
    ushort* Vt = Kx + (size_t)NBH*HW*32;            // 1MB [bh][d][key]
    float*  O  = (float*)(Vt + (size_t)NBH*HW*DH);  // 2MB fp32 [b][p][64]

    hipLaunchKernelGGL(qkv_kernel, dim3(1024), dim3(256), 0, stream,
                       x, illu, qkv_w, qkv_b, illu_w, illu_b, Qx, Kx, Vt);
    hipLaunchKernelGGL(attn_kernel, dim3(512), dim3(512), 0, stream,
                       Qx, Kx, Vt, O);
    hipLaunchKernelGGL(proj_kernel, dim3(1024), dim3(256), 0, stream,
                       O, proj_w, proj_b, out);
}

// Round 11
// 60.929 us; speedup vs baseline: 1.1349x; 1.0134x over previous
//
#include <hip/hip_runtime.h>
#include <hip/hip_bf16.h>
#include <math.h>

#define HW   4096
#define NC   64
#define NB   2
#define NHD  4
#define DH   16
#define NBH  (NB*NHD)

typedef __attribute__((ext_vector_type(4))) float f32x4;
typedef __attribute__((ext_vector_type(8))) short bf16x8;
typedef __attribute__((ext_vector_type(2))) unsigned int uint2v;

#define QSCALE 0.36067376022224087f   // 0.25 * log2(e)

static __device__ __forceinline__ unsigned short bf16_bits(float f) {
    union { __hip_bfloat16 h; unsigned short u; } cv;
    cv.h = __float2bfloat16(f);
    return cv.u;
}
static __device__ __forceinline__ float bits_to_f(unsigned short b) {
    return __uint_as_float(((unsigned int)b) << 16);
}
static __device__ __forceinline__ unsigned int cvt_pk_bf16(float lo, float hi) {
    unsigned int r;
    asm("v_cvt_pk_bf16_f32 %0, %1, %2" : "=v"(r) : "v"(lo), "v"(hi));
    return r;
}

// ---------------------------------------------------------------------------
// Kernel A: qkv + illu 1x1 convs (round-10 verbatim).
// ---------------------------------------------------------------------------
__global__ __launch_bounds__(256) void qkv_kernel(
    const float* __restrict__ x, const float* __restrict__ illu,
    const float* __restrict__ qkv_w, const float* __restrict__ qkv_b,
    const float* __restrict__ illu_w, const float* __restrict__ illu_b,
    ushort* __restrict__ Qx, ushort* __restrict__ Kx, ushort* __restrict__ Vt)
{
    const int PIX = 8;
    __shared__ float  xs[PIX][NC];
    __shared__ float  fs[PIX][NC];
    __shared__ float  kp1[PIX][NC];
    __shared__ float  kp2[PIX][NC];
    __shared__ ushort qs[NHD][PIX][32];
    __shared__ ushort ks[NHD][PIX][32];
    __shared__ ushort vs[NC][PIX];
    int blk = blockIdx.x;                   // 1024
    int b   = blk >> 9;
    int p0  = (blk & 511) * PIX;
    int tid = threadIdx.x;

    if (tid < 128) {
        int ch = tid >> 1, j = tid & 1;
        float4 v = *(const float4*)(x + (size_t)(b*NC + ch)*HW + p0 + 4*j);
        xs[4*j+0][ch] = v.x; xs[4*j+1][ch] = v.y;
        xs[4*j+2][ch] = v.z; xs[4*j+3][ch] = v.w;
    } else {
        int t2 = tid - 128;
        int ch = t2 >> 1, j = t2 & 1;
        float4 v = *(const float4*)(illu + (size_t)(b*NC + ch)*HW + p0 + 4*j);
        fs[4*j+0][ch] = v.x; fs[4*j+1][ch] = v.y;
        fs[4*j+2][ch] = v.z; fs[4*j+3][ch] = v.w;
    }

    int role = tid >> 6;                    // 0=q 1=k_qkv 2=illu 3=v
    int co   = tid & 63;
    int head = co >> 4;
    int dd   = co & 15;

    const float* wrow = (role == 0) ? qkv_w  + (size_t)co*NC
                      : (role == 1) ? qkv_w  + (size_t)(64 + co)*NC
                      : (role == 2) ? illu_w + (size_t)co*NC
                      :               qkv_w  + (size_t)(128 + co)*NC;
    float bias = (role == 0) ? qkv_b[co]
               : (role == 1) ? qkv_b[64 + co]
               : (role == 2) ? illu_b[co]
               :               qkv_b[128 + co];

    float wq[NC];
    #pragma unroll
    for (int c4 = 0; c4 < NC/4; c4++) {
        float4 w = ((const float4*)wrow)[c4];
        wq[4*c4+0] = w.x; wq[4*c4+1] = w.y; wq[4*c4+2] = w.z; wq[4*c4+3] = w.w;
    }
    __syncthreads();

    const float* srcBase = (role == 2) ? &fs[0][0] : &xs[0][0];
    #pragma unroll
    for (int pp = 0; pp < PIX; pp++) {
        float a0 = 0.f, a1 = 0.f, a2 = 0.f, a3 = 0.f;
        const float4* sp = (const float4*)(srcBase + pp*NC);
        #pragma unroll
        for (int c4 = 0; c4 < NC/4; c4++) {
            float4 xv = sp[c4];
            a0 = fmaf(wq[4*c4+0], xv.x, a0);
            a1 = fmaf(wq[4*c4+1], xv.y, a1);
            a2 = fmaf(wq[4*c4+2], xv.z, a2);
            a3 = fmaf(wq[4*c4+3], xv.w, a3);
        }
        float acc = bias + ((a0 + a1) + (a2 + a3));
        if (role == 0) {
            float v = acc * QSCALE;
            unsigned short hb = bf16_bits(v);
            qs[head][pp][dd]      = hb;
            qs[head][pp][16 + dd] = bf16_bits(v - bits_to_f(hb));
        } else if (role == 1) {
            kp1[pp][co] = acc;
        } else if (role == 2) {
            kp2[pp][co] = acc;
        } else {
            vs[co][pp] = bf16_bits(acc);
        }
    }
    __syncthreads();
    if (role == 1) {
        #pragma unroll
        for (int pp = 0; pp < PIX; pp++) {
            float a = kp1[pp][co] + kp2[pp][co];
            unsigned short hb = bf16_bits(a);
            ks[head][pp][dd]      = hb;
            ks[head][pp][16 + dd] = bf16_bits(a - bits_to_f(hb));
        }
    }
    __syncthreads();

    const ushort* qf = &qs[0][0][0];
    const ushort* kf = &ks[0][0][0];
    for (int u = tid; u < 320; u += 256) {
        if (u < 128) {
            int h = u >> 5, inner = u & 31;
            *(bf16x8*)(Qx + ((size_t)(b*NHD + h))*HW*32 + (size_t)p0*32 + inner*8)
                = *(const bf16x8*)(qf + h*PIX*32 + inner*8);
        } else if (u < 256) {
            int h = (u - 128) >> 5, inner = (u - 128) & 31;
            *(bf16x8*)(Kx + ((size_t)(b*NHD + h))*HW*32 + (size_t)p0*32 + inner*8)
                = *(const bf16x8*)(kf + h*PIX*32 + inner*8);
        } else {
            int cc = u - 256;
            *(bf16x8*)(Vt + ((size_t)(b*NC + cc))*HW + p0)
                = *(const bf16x8*)(&vs[cc][0]);
        }
    }
}

// ---------------------------------------------------------------------------
// Kernel B: MFMA flash attention, 4-way split-K, 1 wave per split, 2 q-tiles
// per wave (K/V fragments read ONCE per wave, reused for both q-tiles ->
// 4x fewer LDS reads than round-10). 512 blocks x 512 thr = 8 waves:
// wave w -> split s=w>>1 (keys s*1024..), wave-in-split u=w&1 handles
// q-tiles {2u, 2u+1}. KT=64, per-split double-buffered K,V in LDS; ONE
// barrier per tile; global->reg prefetch overlaps compute. Same per-element
// math as round-10 (K double-bf16 hi|lo, swapped QK^T, bf16 P, no-max
// softmax); only fp32 partial-sum partitioning differs (4x1024 splits).
// Merge reuses Ks LDS. O written as [b][p][64]. LDS = 50KB.
// ---------------------------------------------------------------------------
#define KT   64
#define SPL  4
#define KPS  1024          // keys per split
#define NTS  (KPS/KT)      // 16 tiles per split

__global__ __launch_bounds__(512) void attn_kernel(
    const ushort* __restrict__ Qx, const ushort* __restrict__ Kx,
    const ushort* __restrict__ Vt, float* __restrict__ O)
{
    __shared__ alignas(16) ushort Ks[SPL][2][64*32];  // 32KB [split][buf]
    __shared__ alignas(16) ushort Vs[SPL][2][16*72];  // 18KB [d][64+8pad]

    int blk  = blockIdx.x;               // 512
    int bh   = blk >> 6;
    int q0   = (blk & 63) * 64;
    int tid  = threadIdx.x;              // 0..511
    int w    = tid >> 6;                 // wave 0..7
    int s    = w >> 1;                   // split 0..3
    int u    = w & 1;                    // wave-in-split -> q-tiles 2u,2u+1
    int lane = tid & 63;
    int g    = lane >> 4;                // lane group 0..3
    int qc   = lane & 15;                // query col / A-row / V d-col

    const ushort* Qb = Qx + (size_t)bh*HW*32;
    const ushort* Kb = Kx + (size_t)bh*HW*32 + (size_t)s*KPS*32;
    const ushort* Vb = Vt + (size_t)bh*DH*HW;

    int qrow0 = q0 + (u*2 + 0)*16 + qc;
    int qrow1 = q0 + (u*2 + 1)*16 + qc;
    bf16x8 qhi0 = *(const bf16x8*)(Qb + (size_t)qrow0*32 +      8*(g&1));
    bf16x8 qlo0 = *(const bf16x8*)(Qb + (size_t)qrow0*32 + 16 + 8*(g&1));
    bf16x8 qhi1 = *(const bf16x8*)(Qb + (size_t)qrow1*32 +      8*(g&1));
    bf16x8 qlo1 = *(const bf16x8*)(Qb + (size_t)qrow1*32 + 16 + 8*(g&1));

    f32x4 zero4 = {0.f, 0.f, 0.f, 0.f};
    f32x4 oacc0 = zero4, oacc1 = zero4;
    f32x4 lacc0 = zero4, lacc1 = zero4;

    // compute-side lane-constant addressing
    int mconst = (qc & 3) ^ ((qc >> 2) & 3);
    const int koff = qc*32 + ((g ^ mconst)*8);
    const int voff = qc*72 + 4*g;

    // staging-side: 128 thr per split; K tile 256 chunks (2/thr), V 128 (1/thr)
    int gt = tid & 127;
    int f0 = gt,        r0 = f0 >> 2, h0 = f0 & 3;
    int f1 = gt + 128,  r1 = f1 >> 2, h1 = f1 & 3;
    int s0 = (h0 ^ ((r0 & 3) ^ ((r0 >> 2) & 3))) * 8;
    int s1 = (h1 ^ ((r1 & 3) ^ ((r1 >> 2) & 3))) * 8;
    int vd = gt >> 3, vseg = gt & 7;

    // prologue: tile 0 of this split -> regs -> buf0
    bf16x8 gk0 = *(const bf16x8*)(Kb + (size_t)r0*32 + 8*h0);
    bf16x8 gk1 = *(const bf16x8*)(Kb + (size_t)r1*32 + 8*h1);
    bf16x8 gv  = *(const bf16x8*)(Vb + (size_t)vd*HW + s*KPS + vseg*8);
    *(bf16x8*)(&Ks[s][0][0] + r0*32 + s0) = gk0;
    *(bf16x8*)(&Ks[s][0][0] + r1*32 + s1) = gk1;
    *(bf16x8*)(&Vs[s][0][0] + vd*72 + vseg*8) = gv;

    for (int t = 0; t < NTS; ++t) {
        __syncthreads();
        if (t + 1 < NTS) {               // prefetch tile t+1 into regs
            int kt = (t + 1) * KT;
            gk0 = *(const bf16x8*)(Kb + (size_t)(kt + r0)*32 + 8*h0);
            gk1 = *(const bf16x8*)(Kb + (size_t)(kt + r1)*32 + 8*h1);
            gv  = *(const bf16x8*)(Vb + (size_t)vd*HW + s*KPS + kt + vseg*8);
        }

        const ushort* kr = &Ks[s][t & 1][0] + koff;
        const ushort* vr = &Vs[s][t & 1][0] + voff;
        unsigned int pe00 = 0, pe01 = 0, pe10 = 0, pe11 = 0;
        #pragma unroll
        for (int kb = 0; kb < 4; ++kb) {
            bf16x8 kfrag = *(const bf16x8*)(kr + kb*512);
            // q-tile 0
            f32x4 sA = __builtin_amdgcn_mfma_f32_16x16x32_bf16(kfrag, qhi0, zero4, 0, 0, 0);
            sA = __builtin_amdgcn_mfma_f32_16x16x32_bf16(kfrag, qlo0, sA, 0, 0, 0);
            float a0 = __builtin_amdgcn_exp2f(sA.x);
            float a1 = __builtin_amdgcn_exp2f(sA.y);
            float a2 = __builtin_amdgcn_exp2f(sA.z);
            float a3 = __builtin_amdgcn_exp2f(sA.w);
            lacc0.x += a0; lacc0.y += a1; lacc0.z += a2; lacc0.w += a3;
            unsigned int alo = cvt_pk_bf16(a0, a1);
            unsigned int ahi = cvt_pk_bf16(a2, a3);
            // q-tile 1
            f32x4 sB = __builtin_amdgcn_mfma_f32_16x16x32_bf16(kfrag, qhi1, zero4, 0, 0, 0);
            sB = __builtin_amdgcn_mfma_f32_16x16x32_bf16(kfrag, qlo1, sB, 0, 0, 0);
            float b0 = __builtin_amdgcn_exp2f(sB.x);
            float b1 = __builtin_amdgcn_exp2f(sB.y);
            float b2 = __builtin_amdgcn_exp2f(sB.z);
            float b3 = __builtin_amdgcn_exp2f(sB.w);
            lacc1.x += b0; lacc1.y += b1; lacc1.z += b2; lacc1.w += b3;
            unsigned int blo = cvt_pk_bf16(b0, b1);
            unsigned int bhi = cvt_pk_bf16(b2, b3);

            if ((kb & 1) == 0) { pe00 = alo; pe01 = ahi; pe10 = blo; pe11 = bhi; }
            else {
                uint2v vE = *(const uint2v*)(vr + (kb-1)*16);   // shared j=0,1
                uint2v vO = *(const uint2v*)(vr + kb*16);
                union { unsigned int uu[4]; bf16x8 h; } pa, vv;
                vv.uu[0] = vE.x; vv.uu[1] = vE.y; vv.uu[2] = vO.x; vv.uu[3] = vO.y;
                pa.uu[0] = pe00; pa.uu[1] = pe01; pa.uu[2] = alo; pa.uu[3] = ahi;
                oacc0 = __builtin_amdgcn_mfma_f32_16x16x32_bf16(pa.h, vv.h, oacc0, 0, 0, 0);
                pa.uu[0] = pe10; pa.uu[1] = pe11; pa.uu[2] = blo; pa.uu[3] = bhi;
                oacc1 = __builtin_amdgcn_mfma_f32_16x16x32_bf16(pa.h, vv.h, oacc1, 0, 0, 0);
            }
        }

        if (t + 1 < NTS) {               // write prefetched regs -> other buf
            int nb = (t + 1) & 1;
            *(bf16x8*)(&Ks[s][nb][0] + r0*32 + s0) = gk0;
            *(bf16x8*)(&Ks[s][nb][0] + r1*32 + s1) = gk1;
            *(bf16x8*)(&Vs[s][nb][0] + vd*72 + vseg*8) = gv;
        }
    }

    // split-local denominator reduce (per q-tile)
    float l0 = (lacc0.x + lacc0.y) + (lacc0.z + lacc0.w);
    l0 += __shfl_xor(l0, 16);
    l0 += __shfl_xor(l0, 32);
    float l1 = (lacc1.x + lacc1.y) + (lacc1.z + lacc1.w);
    l1 += __shfl_xor(l1, 16);
    l1 += __shfl_xor(l1, 32);

    // merge splits 1..3 -> split 0, reusing Ks LDS (staging dead now)
    __syncthreads();
    float* mrgF = (float*)&Ks[0][0][0];   // [3][2u][2j][64][5] = 15360 B
    if (s > 0) {
        float* m0 = mrgF + (((((s-1)*2 + u)*2 + 0)*64 + lane)*5);
        m0[0] = oacc0.x; m0[1] = oacc0.y; m0[2] = oacc0.z; m0[3] = oacc0.w; m0[4] = l0;
        float* m1 = mrgF + (((((s-1)*2 + u)*2 + 1)*64 + lane)*5);
        m1[0] = oacc1.x; m1[1] = oacc1.y; m1[2] = oacc1.z; m1[3] = oacc1.w; m1[4] = l1;
    }
    __syncthreads();
    if (s == 0) {
        #pragma unroll
        for (int sp = 0; sp < 3; ++sp) {
            const float* m0 = mrgF + ((((sp*2 + u)*2 + 0)*64 + lane)*5);
            oacc0.x += m0[0]; oacc0.y += m0[1]; oacc0.z += m0[2]; oacc0.w += m0[3];
            l0 += m0[4];
            const float* m1 = mrgF + ((((sp*2 + u)*2 + 1)*64 + lane)*5);
            oacc1.x += m1[0]; oacc1.y += m1[1]; oacc1.z += m1[2]; oacc1.w += m1[3];
            l1 += m1[4];
        }
        int b = bh >> 2, h = bh & 3;
        float* Ob0 = O + ((size_t)b*HW + q0 + (u*2 + 0)*16)*NC + h*DH;
        float* Ob1 = O + ((size_t)b*HW + q0 + (u*2 + 1)*16)*NC + h*DH;
        #pragma unroll
        for (int r = 0; r < 4; ++r) {
            float lr0 = __shfl(l0, 4*g + r);
            float ov0 = (r==0? oacc0.x : r==1? oacc0.y : r==2? oacc0.z : oacc0.w);
            Ob0[(4*g + r)*NC + qc] = ov0 / lr0;
            float lr1 = __shfl(l1, 4*g + r);
            float ov1 = (r==0? oacc1.x : r==1? oacc1.y : r==2? oacc1.z : oacc1.w);
            Ob1[(4*g + r)*NC + qc] = ov1 / lr1;
        }
    }
}

// ---------------------------------------------------------------------------
// Kernel C: proj 1x1 conv + transpose (round-10 verbatim).
// ---------------------------------------------------------------------------
__global__ __launch_bounds__(256) void proj_kernel(
    const float* __restrict__ O, const float* __restrict__ proj_w,
    const float* __restrict__ proj_b, float* __restrict__ y)
{
    const int PIX = 8;
    __shared__ float os[PIX][NC];
    __shared__ float ys[NC][PIX+1];
    int blk = blockIdx.x;                // 1024
    int b   = blk >> 9;
    int p0  = (blk & 511) * PIX;
    int tid = threadIdx.x;
    int c   = tid & 63;
    int pg  = tid >> 6;

    if (tid < PIX*NC/4) {
        int pp = tid >> 4, c4 = tid & 15;
        ((float4*)os[pp])[c4] = ((const float4*)(O + ((size_t)(b*HW + p0 + pp))*NC))[c4];
    }
    float wv[NC];
    #pragma unroll
    for (int c4 = 0; c4 < NC/4; c4++) {
        float4 t = ((const float4*)(proj_w + (size_t)c*NC))[c4];
        wv[4*c4+0] = t.x; wv[4*c4+1] = t.y; wv[4*c4+2] = t.z; wv[4*c4+3] = t.w;
    }
    float bias = proj_b[c];
    __syncthreads();

    #pragma unroll
    for (int u = 0; u < 2; ++u) {
        int pi = pg*2 + u;
        float a0 = 0.f, a1 = 0.f, a2 = 0.f, a3 = 0.f;
        #pragma unroll
        for (int c4 = 0; c4 < NC/4; c4++) {
            float4 ov = ((const float4*)os[pi])[c4];
            a0 = fmaf(wv[4*c4+0], ov.x, a0);
            a1 = fmaf(wv[4*c4+1], ov.y, a1);
            a2 = fmaf(wv[4*c4+2], ov.z, a2);
            a3 = fmaf(wv[4*c4+3], ov.w, a3);
        }
        ys[c][pi] = bias + ((a0 + a1) + (a2 + a3));
    }
    __syncthreads();
    for (int idx = tid; idx < PIX*NC; idx += 256) {
        int cc = idx >> 3;
        int i  = idx & 7;
        y[(size_t)(b*NC + cc)*HW + p0 + i] = ys[cc][i];
    }
}

// ---------------------------------------------------------------------------
extern "C" void kernel_launch(void* const* d_in, const int* in_sizes, int n_in,
                              void* d_out, int out_size, void* d_ws, size_t ws_size,
                              hipStream_t stream)
{
    const float* x      = (const float*)d_in[0];
    const float* illu   = (const float*)d_in[1];
    const float* qkv_w  = (const float*)d_in[2];
    const float* qkv_b  = (const float*)d_in[3];
    const float* illu_w = (const float*)d_in[4];
    const float* illu_b = (const float*)d_in[5];
    const float* proj_w = (const float*)d_in[6];
    const float* proj_b = (const float*)d_in[7];
    float* out = (float*)d_out;

    ushort* Qx = (ushort*)d_ws;                     // 2MB (hi|lo)
    ushort* Kx = Qx + (size_t)NBH*HW*32;            // 2MB (hi|lo)
    ushort* Vt = Kx + (size_t)NBH*HW*32;            // 1MB [bh][d][key]
    float*  O  = (float*)(Vt + (size_t)NBH*HW*DH);  // 2MB fp32 [b][p][64]

    hipLaunchKernelGGL(qkv_kernel, dim3(1024), dim3(256), 0, stream,
                       x, illu, qkv_w, qkv_b, illu_w, illu_b, Qx, Kx, Vt);
    hipLaunchKernelGGL(attn_kernel, dim3(512), dim3(512), 0, stream,
                       Qx, Kx, Vt, O);
    hipLaunchKernelGGL(proj_kernel, dim3(1024), dim3(256), 0, stream,
                       O, proj_w, proj_b, out);
}

// Round 12
// 60.309 us; speedup vs baseline: 1.1466x; 1.0103x over previous
//
#include <hip/hip_runtime.h>
#include <hip/hip_bf16.h>
#include <math.h>

#define HW   4096
#define NC   64
#define NB   2
#define NHD  4
#define DH   16
#define NBH  (NB*NHD)

typedef __attribute__((ext_vector_type(4))) float f32x4;
typedef __attribute__((ext_vector_type(8))) short bf16x8;
typedef __attribute__((ext_vector_type(2))) unsigned int uint2v;

#define QSCALE 0.36067376022224087f   // 0.25 * log2(e)

static __device__ __forceinline__ unsigned short bf16_bits(float f) {
    union { __hip_bfloat16 h; unsigned short u; } cv;
    cv.h = __float2bfloat16(f);
    return cv.u;
}
static __device__ __forceinline__ float bits_to_f(unsigned short b) {
    return __uint_as_float(((unsigned int)b) << 16);
}
static __device__ __forceinline__ unsigned int cvt_pk_bf16(float lo, float hi) {
    unsigned int r;
    asm("v_cvt_pk_bf16_f32 %0, %1, %2" : "=v"(r) : "v"(lo), "v"(hi));
    return r;
}

// ---------------------------------------------------------------------------
// Kernel A: qkv + illu 1x1 convs (round-10 verbatim).
// ---------------------------------------------------------------------------
__global__ __launch_bounds__(256) void qkv_kernel(
    const float* __restrict__ x, const float* __restrict__ illu,
    const float* __restrict__ qkv_w, const float* __restrict__ qkv_b,
    const float* __restrict__ illu_w, const float* __restrict__ illu_b,
    ushort* __restrict__ Qx, ushort* __restrict__ Kx, ushort* __restrict__ Vt)
{
    const int PIX = 8;
    __shared__ float  xs[PIX][NC];
    __shared__ float  fs[PIX][NC];
    __shared__ float  kp1[PIX][NC];
    __shared__ float  kp2[PIX][NC];
    __shared__ ushort qs[NHD][PIX][32];
    __shared__ ushort ks[NHD][PIX][32];
    __shared__ ushort vs[NC][PIX];
    int blk = blockIdx.x;                   // 1024
    int b   = blk >> 9;
    int p0  = (blk & 511) * PIX;
    int tid = threadIdx.x;

    if (tid < 128) {
        int ch = tid >> 1, j = tid & 1;
        float4 v = *(const float4*)(x + (size_t)(b*NC + ch)*HW + p0 + 4*j);
        xs[4*j+0][ch] = v.x; xs[4*j+1][ch] = v.y;
        xs[4*j+2][ch] = v.z; xs[4*j+3][ch] = v.w;
    } else {
        int t2 = tid - 128;
        int ch = t2 >> 1, j = t2 & 1;
        float4 v = *(const float4*)(illu + (size_t)(b*NC + ch)*HW + p0 + 4*j);
        fs[4*j+0][ch] = v.x; fs[4*j+1][ch] = v.y;
        fs[4*j+2][ch] = v.z; fs[4*j+3][ch] = v.w;
    }

    int role = tid >> 6;                    // 0=q 1=k_qkv 2=illu 3=v
    int co   = tid & 63;
    int head = co >> 4;
    int dd   = co & 15;

    const float* wrow = (role == 0) ? qkv_w  + (size_t)co*NC
                      : (role == 1) ? qkv_w  + (size_t)(64 + co)*NC
                      : (role == 2) ? illu_w + (size_t)co*NC
                      :               qkv_w  + (size_t)(128 + co)*NC;
    float bias = (role == 0) ? qkv_b[co]
               : (role == 1) ? qkv_b[64 + co]
               : (role == 2) ? illu_b[co]
               :               qkv_b[128 + co];

    float wq[NC];
    #pragma unroll
    for (int c4 = 0; c4 < NC/4; c4++) {
        float4 w = ((const float4*)wrow)[c4];
        wq[4*c4+0] = w.x; wq[4*c4+1] = w.y; wq[4*c4+2] = w.z; wq[4*c4+3] = w.w;
    }
    __syncthreads();

    const float* srcBase = (role == 2) ? &fs[0][0] : &xs[0][0];
    #pragma unroll
    for (int pp = 0; pp < PIX; pp++) {
        float a0 = 0.f, a1 = 0.f, a2 = 0.f, a3 = 0.f;
        const float4* sp = (const float4*)(srcBase + pp*NC);
        #pragma unroll
        for (int c4 = 0; c4 < NC/4; c4++) {
            float4 xv = sp[c4];
            a0 = fmaf(wq[4*c4+0], xv.x, a0);
            a1 = fmaf(wq[4*c4+1], xv.y, a1);
            a2 = fmaf(wq[4*c4+2], xv.z, a2);
            a3 = fmaf(wq[4*c4+3], xv.w, a3);
        }
        float acc = bias + ((a0 + a1) + (a2 + a3));
        if (role == 0) {
            float v = acc * QSCALE;
            unsigned short hb = bf16_bits(v);
            qs[head][pp][dd]      = hb;
            qs[head][pp][16 + dd] = bf16_bits(v - bits_to_f(hb));
        } else if (role == 1) {
            kp1[pp][co] = acc;
        } else if (role == 2) {
            kp2[pp][co] = acc;
        } else {
            vs[co][pp] = bf16_bits(acc);
        }
    }
    __syncthreads();
    if (role == 1) {
        #pragma unroll
        for (int pp = 0; pp < PIX; pp++) {
            float a = kp1[pp][co] + kp2[pp][co];
            unsigned short hb = bf16_bits(a);
            ks[head][pp][dd]      = hb;
            ks[head][pp][16 + dd] = bf16_bits(a - bits_to_f(hb));
        }
    }
    __syncthreads();

    const ushort* qf = &qs[0][0][0];
    const ushort* kf = &ks[0][0][0];
    for (int u = tid; u < 320; u += 256) {
        if (u < 128) {
            int h = u >> 5, inner = u & 31;
            *(bf16x8*)(Qx + ((size_t)(b*NHD + h))*HW*32 + (size_t)p0*32 + inner*8)
                = *(const bf16x8*)(qf + h*PIX*32 + inner*8);
        } else if (u < 256) {
            int h = (u - 128) >> 5, inner = (u - 128) & 31;
            *(bf16x8*)(Kx + ((size_t)(b*NHD + h))*HW*32 + (size_t)p0*32 + inner*8)
                = *(const bf16x8*)(kf + h*PIX*32 + inner*8);
        } else {
            int cc = u - 256;
            *(bf16x8*)(Vt + ((size_t)(b*NC + cc))*HW + p0)
                = *(const bf16x8*)(&vs[cc][0]);
        }
    }
}

// ---------------------------------------------------------------------------
// Kernel B: MFMA flash attention (round-11 structure, bit-identical math)
// + XCD-affine block mapping (bh = blk&7: all 64 blocks of one bh land on
//   one XCD's L2 via round-robin dispatch) 
// + prefetch depth 2 (loads for tile t+2 issued at tile t; ~1000-cyc window
//   covers HBM-miss latency; LDS stays double-buffered, 1 barrier/tile).
// 4-way split-K, 1 wave/split, 2 q-tiles/wave, KT=64. LDS 50KB.
// ---------------------------------------------------------------------------
#define KT   64
#define SPL  4
#define KPS  1024          // keys per split
#define NTS  (KPS/KT)      // 16 tiles per split

__global__ __launch_bounds__(512) void attn_kernel(
    const ushort* __restrict__ Qx, const ushort* __restrict__ Kx,
    const ushort* __restrict__ Vt, float* __restrict__ O)
{
    __shared__ alignas(16) ushort Ks[SPL][2][64*32];  // 32KB [split][buf]
    __shared__ alignas(16) ushort Vs[SPL][2][16*72];  // 18KB [d][64+8pad]

    int blk  = blockIdx.x;               // 512
    int bh   = blk & 7;                  // XCD-affine: bh j -> XCD j
    int q0   = (blk >> 3) * 64;
    int tid  = threadIdx.x;              // 0..511
    int w    = tid >> 6;                 // wave 0..7
    int s    = w >> 1;                   // split 0..3
    int u    = w & 1;                    // wave-in-split -> q-tiles 2u,2u+1
    int lane = tid & 63;
    int g    = lane >> 4;                // lane group 0..3
    int qc   = lane & 15;                // query col / A-row / V d-col

    const ushort* Qb = Qx + (size_t)bh*HW*32;
    const ushort* Kb = Kx + (size_t)bh*HW*32 + (size_t)s*KPS*32;
    const ushort* Vb = Vt + (size_t)bh*DH*HW;

    int qrow0 = q0 + (u*2 + 0)*16 + qc;
    int qrow1 = q0 + (u*2 + 1)*16 + qc;
    bf16x8 qhi0 = *(const bf16x8*)(Qb + (size_t)qrow0*32 +      8*(g&1));
    bf16x8 qlo0 = *(const bf16x8*)(Qb + (size_t)qrow0*32 + 16 + 8*(g&1));
    bf16x8 qhi1 = *(const bf16x8*)(Qb + (size_t)qrow1*32 +      8*(g&1));
    bf16x8 qlo1 = *(const bf16x8*)(Qb + (size_t)qrow1*32 + 16 + 8*(g&1));

    f32x4 zero4 = {0.f, 0.f, 0.f, 0.f};
    f32x4 oacc0 = zero4, oacc1 = zero4;
    f32x4 lacc0 = zero4, lacc1 = zero4;

    // compute-side lane-constant addressing
    int mconst = (qc & 3) ^ ((qc >> 2) & 3);
    const int koff = qc*32 + ((g ^ mconst)*8);
    const int voff = qc*72 + 4*g;

    // staging-side: 128 thr per split; K tile 256 chunks (2/thr), V 128 (1/thr)
    int gt = tid & 127;
    int f0 = gt,        r0 = f0 >> 2, h0 = f0 & 3;
    int f1 = gt + 128,  r1 = f1 >> 2, h1 = f1 & 3;
    int s0 = (h0 ^ ((r0 & 3) ^ ((r0 >> 2) & 3))) * 8;
    int s1 = (h1 ^ ((r1 & 3) ^ ((r1 >> 2) & 3))) * 8;
    int vd = gt >> 3, vseg = gt & 7;

    // prologue: tile 0 -> buf0; tile 1 in-flight (set B)
    {
        bf16x8 a0 = *(const bf16x8*)(Kb + (size_t)r0*32 + 8*h0);
        bf16x8 a1 = *(const bf16x8*)(Kb + (size_t)r1*32 + 8*h1);
        bf16x8 av = *(const bf16x8*)(Vb + (size_t)vd*HW + s*KPS + vseg*8);
        *(bf16x8*)(&Ks[s][0][0] + r0*32 + s0) = a0;
        *(bf16x8*)(&Ks[s][0][0] + r1*32 + s1) = a1;
        *(bf16x8*)(&Vs[s][0][0] + vd*72 + vseg*8) = av;
    }
    bf16x8 k0b = *(const bf16x8*)(Kb + (size_t)(KT + r0)*32 + 8*h0);
    bf16x8 k1b = *(const bf16x8*)(Kb + (size_t)(KT + r1)*32 + 8*h1);
    bf16x8 vb_ = *(const bf16x8*)(Vb + (size_t)vd*HW + s*KPS + KT + vseg*8);

    for (int t = 0; t < NTS; ++t) {
        __syncthreads();
        bf16x8 k0c = k0b, k1c = k1b, vc_ = vb_;
        if (t + 2 < NTS) {               // issue loads for tile t+2 (depth 2)
            int kt = (t + 2) * KT;
            k0c = *(const bf16x8*)(Kb + (size_t)(kt + r0)*32 + 8*h0);
            k1c = *(const bf16x8*)(Kb + (size_t)(kt + r1)*32 + 8*h1);
            vc_ = *(const bf16x8*)(Vb + (size_t)vd*HW + s*KPS + kt + vseg*8);
        }

        const ushort* kr = &Ks[s][t & 1][0] + koff;
        const ushort* vr = &Vs[s][t & 1][0] + voff;
        unsigned int pe00 = 0, pe01 = 0, pe10 = 0, pe11 = 0;
        #pragma unroll
        for (int kb = 0; kb < 4; ++kb) {
            bf16x8 kfrag = *(const bf16x8*)(kr + kb*512);
            // q-tile 0
            f32x4 sA = __builtin_amdgcn_mfma_f32_16x16x32_bf16(kfrag, qhi0, zero4, 0, 0, 0);
            sA = __builtin_amdgcn_mfma_f32_16x16x32_bf16(kfrag, qlo0, sA, 0, 0, 0);
            float a0 = __builtin_amdgcn_exp2f(sA.x);
            float a1 = __builtin_amdgcn_exp2f(sA.y);
            float a2 = __builtin_amdgcn_exp2f(sA.z);
            float a3 = __builtin_amdgcn_exp2f(sA.w);
            lacc0.x += a0; lacc0.y += a1; lacc0.z += a2; lacc0.w += a3;
            unsigned int alo = cvt_pk_bf16(a0, a1);
            unsigned int ahi = cvt_pk_bf16(a2, a3);
            // q-tile 1
            f32x4 sB = __builtin_amdgcn_mfma_f32_16x16x32_bf16(kfrag, qhi1, zero4, 0, 0, 0);
            sB = __builtin_amdgcn_mfma_f32_16x16x32_bf16(kfrag, qlo1, sB, 0, 0, 0);
            float b0 = __builtin_amdgcn_exp2f(sB.x);
            float b1 = __builtin_amdgcn_exp2f(sB.y);
            float b2 = __builtin_amdgcn_exp2f(sB.z);
            float b3 = __builtin_amdgcn_exp2f(sB.w);
            lacc1.x += b0; lacc1.y += b1; lacc1.z += b2; lacc1.w += b3;
            unsigned int blo = cvt_pk_bf16(b0, b1);
            unsigned int bhi = cvt_pk_bf16(b2, b3);

            if ((kb & 1) == 0) { pe00 = alo; pe01 = ahi; pe10 = blo; pe11 = bhi; }
            else {
                uint2v vE = *(const uint2v*)(vr + (kb-1)*16);
                uint2v vO = *(const uint2v*)(vr + kb*16);
                union { unsigned int uu[4]; bf16x8 h; } pa, vv;
                vv.uu[0] = vE.x; vv.uu[1] = vE.y; vv.uu[2] = vO.x; vv.uu[3] = vO.y;
                pa.uu[0] = pe00; pa.uu[1] = pe01; pa.uu[2] = alo; pa.uu[3] = ahi;
                oacc0 = __builtin_amdgcn_mfma_f32_16x16x32_bf16(pa.h, vv.h, oacc0, 0, 0, 0);
                pa.uu[0] = pe10; pa.uu[1] = pe11; pa.uu[2] = blo; pa.uu[3] = bhi;
                oacc1 = __builtin_amdgcn_mfma_f32_16x16x32_bf16(pa.h, vv.h, oacc1, 0, 0, 0);
            }
        }

        if (t + 1 < NTS) {               // write in-flight tile t+1 -> other buf
            int nb = (t + 1) & 1;
            *(bf16x8*)(&Ks[s][nb][0] + r0*32 + s0) = k0b;
            *(bf16x8*)(&Ks[s][nb][0] + r1*32 + s1) = k1b;
            *(bf16x8*)(&Vs[s][nb][0] + vd*72 + vseg*8) = vb_;
            k0b = k0c; k1b = k1c; vb_ = vc_;
        }
    }

    // split-local denominator reduce (per q-tile)
    float l0 = (lacc0.x + lacc0.y) + (lacc0.z + lacc0.w);
    l0 += __shfl_xor(l0, 16);
    l0 += __shfl_xor(l0, 32);
    float l1 = (lacc1.x + lacc1.y) + (lacc1.z + lacc1.w);
    l1 += __shfl_xor(l1, 16);
    l1 += __shfl_xor(l1, 32);

    // merge splits 1..3 -> split 0, reusing Ks LDS (staging dead now)
    __syncthreads();
    float* mrgF = (float*)&Ks[0][0][0];   // [3][2u][2j][64][5] = 15360 B
    if (s > 0) {
        float* m0 = mrgF + (((((s-1)*2 + u)*2 + 0)*64 + lane)*5);
        m0[0] = oacc0.x; m0[1] = oacc0.y; m0[2] = oacc0.z; m0[3] = oacc0.w; m0[4] = l0;
        float* m1 = mrgF + (((((s-1)*2 + u)*2 + 1)*64 + lane)*5);
        m1[0] = oacc1.x; m1[1] = oacc1.y; m1[2] = oacc1.z; m1[3] = oacc1.w; m1[4] = l1;
    }
    __syncthreads();
    if (s == 0) {
        #pragma unroll
        for (int sp = 0; sp < 3; ++sp) {
            const float* m0 = mrgF + ((((sp*2 + u)*2 + 0)*64 + lane)*5);
            oacc0.x += m0[0]; oacc0.y += m0[1]; oacc0.z += m0[2]; oacc0.w += m0[3];
            l0 += m0[4];
            const float* m1 = mrgF + ((((sp*2 + u)*2 + 1)*64 + lane)*5);
            oacc1.x += m1[0]; oacc1.y += m1[1]; oacc1.z += m1[2]; oacc1.w += m1[3];
            l1 += m1[4];
        }
        int b = bh >> 2, h = bh & 3;
        float* Ob0 = O + ((size_t)b*HW + q0 + (u*2 + 0)*16)*NC + h*DH;
        float* Ob1 = O + ((size_t)b*HW + q0 + (u*2 + 1)*16)*NC + h*DH;
        #pragma unroll
        for (int r = 0; r < 4; ++r) {
            float lr0 = __shfl(l0, 4*g + r);
            float ov0 = (r==0? oacc0.x : r==1? oacc0.y : r==2? oacc0.z : oacc0.w);
            Ob0[(4*g + r)*NC + qc] = ov0 / lr0;
            float lr1 = __shfl(l1, 4*g + r);
            float ov1 = (r==0? oacc1.x : r==1? oacc1.y : r==2? oacc1.z : oacc1.w);
            Ob1[(4*g + r)*NC + qc] = ov1 / lr1;
        }
    }
}

// ---------------------------------------------------------------------------
// Kernel C: proj 1x1 conv + transpose (round-10 verbatim).
// ---------------------------------------------------------------------------
__global__ __launch_bounds__(256) void proj_kernel(
    const float* __restrict__ O, const float* __restrict__ proj_w,
    const float* __restrict__ proj_b, float* __restrict__ y)
{
    const int PIX = 8;
    __shared__ float os[PIX][NC];
    __shared__ float ys[NC][PIX+1];
    int blk = blockIdx.x;                // 1024
    int b   = blk >> 9;
    int p0  = (blk & 511) * PIX;
    int tid = threadIdx.x;
    int c   = tid & 63;
    int pg  = tid >> 6;

    if (tid < PIX*NC/4) {
        int pp = tid >> 4, c4 = tid & 15;
        ((float4*)os[pp])[c4] = ((const float4*)(O + ((size_t)(b*HW + p0 + pp))*NC))[c4];
    }
    float wv[NC];
    #pragma unroll
    for (int c4 = 0; c4 < NC/4; c4++) {
        float4 t = ((const float4*)(proj_w + (size_t)c*NC))[c4];
        wv[4*c4+0] = t.x; wv[4*c4+1] = t.y; wv[4*c4+2] = t.z; wv[4*c4+3] = t.w;
    }
    float bias = proj_b[c];
    __syncthreads();

    #pragma unroll
    for (int u = 0; u < 2; ++u) {
        int pi = pg*2 + u;
        float a0 = 0.f, a1 = 0.f, a2 = 0.f, a3 = 0.f;
        #pragma unroll
        for (int c4 = 0; c4 < NC/4; c4++) {
            float4 ov = ((const float4*)os[pi])[c4];
            a0 = fmaf(wv[4*c4+0], ov.x, a0);
            a1 = fmaf(wv[4*c4+1], ov.y, a1);
            a2 = fmaf(wv[4*c4+2], ov.z, a2);
            a3 = fmaf(wv[4*c4+3], ov.w, a3);
        }
        ys[c][pi] = bias + ((a0 + a1) + (a2 + a3));
    }
    __syncthreads();
    for (int idx = tid; idx < PIX*NC; idx += 256) {
        int cc = idx >> 3;
        int i  = idx & 7;
        y[(size_t)(b*NC + cc)*HW + p0 + i] = ys[cc][i];
    }
}

// ---------------------------------------------------------------------------
extern "C" void kernel_launch(void* const* d_in, const int* in_sizes, int n_in,
                              void* d_out, int out_size, void* d_ws, size_t ws_size,
                              hipStream_t stream)
{
    const float* x      = (const float*)d_in[0];
    const float* illu   = (const float*)d_in[1];
    const float* qkv_w  = (const float*)d_in[2];
    const float* qkv_b  = (const float*)d_in[3];
    const float* illu_w = (const float*)d_in[4];
    const float* illu_b = (const float*)d_in[5];
    const float* proj_w = (const float*)d_in[6];
    const float* proj_b = (const float*)d_in[7];
    float* out = (float*)d_out;

    ushort* Qx = (ushort*)d_ws;                     // 2MB (hi|lo)
    ushort* Kx = Qx + (size_t)NBH*HW*32;            // 2MB (hi|lo)
    ushort* Vt = Kx + (size_t)NBH*HW*32;            // 1MB [bh][d][key]
    float*  O  = (float*)(Vt + (size_t)NBH*HW*DH);  // 2MB fp32 [b][p][64]

    hipLaunchKernelGGL(qkv_kernel, dim3(1024), dim3(256), 0, stream,
                       x, illu, qkv_w, qkv_b, illu_w, illu_b, Qx, Kx, Vt);
    hipLaunchKernelGGL(attn_kernel, dim3(512), dim3(512), 0, stream,
                       Qx, Kx, Vt, O);
    hipLaunchKernelGGL(proj_kernel, dim3(1024), dim3(256), 0, stream,
                       O, proj_w, proj_b, out);
}

// Round 13
// 54.919 us; speedup vs baseline: 1.2591x; 1.0981x over previous
//
#include <hip/hip_runtime.h>
#include <hip/hip_bf16.h>
#include <math.h>

#define HW   4096
#define NC   64
#define NB   2
#define NHD  4
#define DH   16
#define NBH  (NB*NHD)

typedef __attribute__((ext_vector_type(4))) float f32x4;
typedef __attribute__((ext_vector_type(8))) short bf16x8;
typedef __attribute__((ext_vector_type(2))) unsigned int uint2v;

#define QSCALE 0.36067376022224087f   // 0.25 * log2(e)

static __device__ __forceinline__ unsigned short bf16_bits(float f) {
    union { __hip_bfloat16 h; unsigned short u; } cv;
    cv.h = __float2bfloat16(f);
    return cv.u;
}
static __device__ __forceinline__ float bits_to_f(unsigned short b) {
    return __uint_as_float(((unsigned int)b) << 16);
}
static __device__ __forceinline__ unsigned int cvt_pk_bf16(float lo, float hi) {
    unsigned int r;
    asm("v_cvt_pk_bf16_f32 %0, %1, %2" : "=v"(r) : "v"(lo), "v"(hi));
    return r;
}

// ---------------------------------------------------------------------------
// Kernel W: weight prep for the qkv MFMA GEMM.
// Wt layout [ot 12][ct 8][hl 2][n 16][16] bf16 (B-frag-ready: lane (g,n)
// reads 8 contiguous = W_hl rows 8(g&1)..+7 at out-col n).
// z-input = [x(64); f(64)]: q rows (ot 0-3): [Wq*QSCALE | 0];
// k rows (4-7): [Wk | Wi]; v rows (8-11): [Wv | 0].
// Bias[192]: q: qkv_b*QSCALE; k: qkv_b + illu_b; v: qkv_b.
// ---------------------------------------------------------------------------
__global__ __launch_bounds__(256) void wprep_kernel(
    const float* __restrict__ qkv_w, const float* __restrict__ qkv_b,
    const float* __restrict__ illu_w, const float* __restrict__ illu_b,
    ushort* __restrict__ Wt, float* __restrict__ Bias)
{
    int idx = blockIdx.x * 256 + threadIdx.x;
    if (idx < 49152) {
        int k8 = idx & 15;
        int n  = (idx >> 4) & 15;
        int hl = (idx >> 8) & 1;
        int ct = (idx >> 9) & 7;
        int ot = idx >> 12;              // 0..11
        int c   = ct*16 + k8;            // 0..127 (k8 = 8h + r)
        int out = ot*16 + n;             // 0..191
        float w;
        if (ot < 4)       w = (c < 64) ? qkv_w[out*64 + c] * QSCALE : 0.f;
        else if (ot < 8)  w = (c < 64) ? qkv_w[out*64 + c]
                                       : illu_w[(out-64)*64 + (c-64)];
        else              w = (c < 64) ? qkv_w[out*64 + c] : 0.f;
        unsigned short hb = bf16_bits(w);
        Wt[idx] = (hl == 0) ? hb : bf16_bits(w - bits_to_f(hb));
    } else if (idx < 49152 + 192) {
        int out = idx - 49152;
        float bv = (out < 64)  ? qkv_b[out] * QSCALE
                 : (out < 128) ? qkv_b[out] + illu_b[out-64]
                 :               qkv_b[out];
        Bias[out] = bv;
    }
}

// ---------------------------------------------------------------------------
// Kernel A: qkv+illu as double-bf16 MFMA GEMM. 512 blocks x 256 thr (4 waves),
// 16 pixels/block. Stage x,f fp32 -> LDS; convert to hi/lo bf16 A-frags
// (XOR-swizzled granules, attn's pattern); 12 out-tiles x {4|8} ctiles x
// 2 MFMAs; epilogue writes Qx/Kx (hi|lo) and Vt (packed) in attn's layouts.
// ---------------------------------------------------------------------------
__global__ __launch_bounds__(256) void qkv_kernel(
    const float* __restrict__ x, const float* __restrict__ illu,
    const ushort* __restrict__ Wt, const float* __restrict__ Bias,
    ushort* __restrict__ Qx, ushort* __restrict__ Kx, ushort* __restrict__ Vt)
{
    __shared__ alignas(16) float  xf[128*20];    // [z-row 128][16 px + 4 pad]
    __shared__ alignas(16) ushort frag[8*16*32]; // [ct][px][32 slots swz]

    int blk = blockIdx.x;                // 512
    int b   = blk & 1;
    int px0 = (blk >> 1) * 16;
    int tid = threadIdx.x;
    int w   = tid >> 6;
    int lane = tid & 63;
    int g   = lane >> 4;
    int n   = lane & 15;                 // A-row (px) and B-col (out)

    // stage 1: z = [x; f] fp32 -> LDS [row][20]
    #pragma unroll
    for (int rep = 0; rep < 2; ++rep) {
        int id  = tid + rep*256;
        int row = id >> 2, seg = id & 3;
        const float* src = (row < 64) ? x    + (size_t)(b*NC + row)*HW
                                      : illu + (size_t)(b*NC + row - 64)*HW;
        float4 v = *(const float4*)(src + px0 + seg*4);
        *(float4*)(xf + row*20 + seg*4) = v;
    }
    __syncthreads();

    // stage 2: convert to hi/lo bf16 granules (128 threads)
    if (tid < 128) {
        int ct = tid >> 4, px = tid & 15;
        int swz = (px & 3) ^ ((px >> 2) & 3);
        union { ushort us[8]; bf16x8 v; } g0, g1, g2, g3;
        #pragma unroll
        for (int i = 0; i < 8; ++i) {
            float v  = xf[(ct*16 + i)*20 + px];
            unsigned short hb = bf16_bits(v);
            g0.us[i] = hb;
            g2.us[i] = bf16_bits(v - bits_to_f(hb));
            float v2 = xf[(ct*16 + 8 + i)*20 + px];
            unsigned short hb2 = bf16_bits(v2);
            g1.us[i] = hb2;
            g3.us[i] = bf16_bits(v2 - bits_to_f(hb2));
        }
        ushort* fb = frag + (ct*16 + px)*32;
        *(bf16x8*)(fb + ((0 ^ swz)*8)) = g0.v;
        *(bf16x8*)(fb + ((1 ^ swz)*8)) = g1.v;
        *(bf16x8*)(fb + ((2 ^ swz)*8)) = g2.v;
        *(bf16x8*)(fb + ((3 ^ swz)*8)) = g3.v;
    }
    __syncthreads();

    // GEMM: wave w handles out-tiles w, w+4, w+8 (balanced MFMA counts)
    f32x4 zero4 = {0.f, 0.f, 0.f, 0.f};
    int px  = n;                          // A-row within the 16-px tile
    int swz = (px & 3) ^ ((px >> 2) & 3);
    const ushort* af_base = frag + px*32 + (g ^ swz)*8;

    #pragma unroll
    for (int j = 0; j < 3; ++j) {
        int ot  = w + 4*j;                // 0..11
        int nct = (ot >= 4 && ot < 8) ? 8 : 4;
        f32x4 acc = zero4;
        for (int ct = 0; ct < nct; ++ct) {
            bf16x8 af = *(const bf16x8*)(af_base + ct*512);   // +ct*16*32 ush
            const ushort* wb = Wt + ((size_t)(ot*8 + ct)*2)*256 + n*16 + (g&1)*8;
            bf16x8 bh = *(const bf16x8*)(wb);
            bf16x8 bl = *(const bf16x8*)(wb + 256);
            acc = __builtin_amdgcn_mfma_f32_16x16x32_bf16(af, bh, acc, 0, 0, 0);
            acc = __builtin_amdgcn_mfma_f32_16x16x32_bf16(af, bl, acc, 0, 0, 0);
        }
        float bias = Bias[ot*16 + n];
        float v0 = acc.x + bias, v1 = acc.y + bias;
        float v2 = acc.z + bias, v3 = acc.w + bias;
        if (ot < 8) {                     // q (0-3) or k (4-7): hi|lo u16
            ushort* dst = (ot < 4) ? Qx : Kx;
            int head = ot & 3;
            size_t base = ((size_t)(b*NHD + head))*HW*32;
            #pragma unroll
            for (int r = 0; r < 4; ++r) {
                float val = (r==0? v0 : r==1? v1 : r==2? v2 : v3);
                int pxr = px0 + 4*g + r;
                unsigned short hb = bf16_bits(val);
                dst[base + (size_t)pxr*32 + n]      = hb;
                dst[base + (size_t)pxr*32 + 16 + n] = bf16_bits(val - bits_to_f(hb));
            }
        } else {                          // v: pack 4 consecutive keys, b64
            int co = (ot - 8)*16 + n;
            uint2v pk;
            pk.x = cvt_pk_bf16(v0, v1);
            pk.y = cvt_pk_bf16(v2, v3);
            *(uint2v*)(Vt + ((size_t)(b*NC + co))*HW + px0 + 4*g) = pk;
        }
    }
}

// ---------------------------------------------------------------------------
// Kernel B: MFMA flash attention (round-12 verbatim: 4-way split-K,
// 1 wave/split, 2 q-tiles/wave, KT=64, XCD-affine bh, depth-2 prefetch).
// ---------------------------------------------------------------------------
#define KT   64
#define SPL  4
#define KPS  1024
#define NTS  (KPS/KT)

__global__ __launch_bounds__(512) void attn_kernel(
    const ushort* __restrict__ Qx, const ushort* __restrict__ Kx,
    const ushort* __restrict__ Vt, float* __restrict__ O)
{
    __shared__ alignas(16) ushort Ks[SPL][2][64*32];
    __shared__ alignas(16) ushort Vs[SPL][2][16*72];

    int blk  = blockIdx.x;               // 512
    int bh   = blk & 7;
    int q0   = (blk >> 3) * 64;
    int tid  = threadIdx.x;
    int w    = tid >> 6;
    int s    = w >> 1;
    int u    = w & 1;
    int lane = tid & 63;
    int g    = lane >> 4;
    int qc   = lane & 15;

    const ushort* Qb = Qx + (size_t)bh*HW*32;
    const ushort* Kb = Kx + (size_t)bh*HW*32 + (size_t)s*KPS*32;
    const ushort* Vb = Vt + (size_t)bh*DH*HW;

    int qrow0 = q0 + (u*2 + 0)*16 + qc;
    int qrow1 = q0 + (u*2 + 1)*16 + qc;
    bf16x8 qhi0 = *(const bf16x8*)(Qb + (size_t)qrow0*32 +      8*(g&1));
    bf16x8 qlo0 = *(const bf16x8*)(Qb + (size_t)qrow0*32 + 16 + 8*(g&1));
    bf16x8 qhi1 = *(const bf16x8*)(Qb + (size_t)qrow1*32 +      8*(g&1));
    bf16x8 qlo1 = *(const bf16x8*)(Qb + (size_t)qrow1*32 + 16 + 8*(g&1));

    f32x4 zero4 = {0.f, 0.f, 0.f, 0.f};
    f32x4 oacc0 = zero4, oacc1 = zero4;
    f32x4 lacc0 = zero4, lacc1 = zero4;

    int mconst = (qc & 3) ^ ((qc >> 2) & 3);
    const int koff = qc*32 + ((g ^ mconst)*8);
    const int voff = qc*72 + 4*g;

    int gt = tid & 127;
    int f0 = gt,        r0 = f0 >> 2, h0 = f0 & 3;
    int f1 = gt + 128,  r1 = f1 >> 2, h1 = f1 & 3;
    int s0 = (h0 ^ ((r0 & 3) ^ ((r0 >> 2) & 3))) * 8;
    int s1 = (h1 ^ ((r1 & 3) ^ ((r1 >> 2) & 3))) * 8;
    int vd = gt >> 3, vseg = gt & 7;

    {
        bf16x8 a0 = *(const bf16x8*)(Kb + (size_t)r0*32 + 8*h0);
        bf16x8 a1 = *(const bf16x8*)(Kb + (size_t)r1*32 + 8*h1);
        bf16x8 av = *(const bf16x8*)(Vb + (size_t)vd*HW + s*KPS + vseg*8);
        *(bf16x8*)(&Ks[s][0][0] + r0*32 + s0) = a0;
        *(bf16x8*)(&Ks[s][0][0] + r1*32 + s1) = a1;
        *(bf16x8*)(&Vs[s][0][0] + vd*72 + vseg*8) = av;
    }
    bf16x8 k0b = *(const bf16x8*)(Kb + (size_t)(KT + r0)*32 + 8*h0);
    bf16x8 k1b = *(const bf16x8*)(Kb + (size_t)(KT + r1)*32 + 8*h1);
    bf16x8 vb_ = *(const bf16x8*)(Vb + (size_t)vd*HW + s*KPS + KT + vseg*8);

    for (int t = 0; t < NTS; ++t) {
        __syncthreads();
        bf16x8 k0c = k0b, k1c = k1b, vc_ = vb_;
        if (t + 2 < NTS) {
            int kt = (t + 2) * KT;
            k0c = *(const bf16x8*)(Kb + (size_t)(kt + r0)*32 + 8*h0);
            k1c = *(const bf16x8*)(Kb + (size_t)(kt + r1)*32 + 8*h1);
            vc_ = *(const bf16x8*)(Vb + (size_t)vd*HW + s*KPS + kt + vseg*8);
        }

        const ushort* kr = &Ks[s][t & 1][0] + koff;
        const ushort* vr = &Vs[s][t & 1][0] + voff;
        unsigned int pe00 = 0, pe01 = 0, pe10 = 0, pe11 = 0;
        #pragma unroll
        for (int kb = 0; kb < 4; ++kb) {
            bf16x8 kfrag = *(const bf16x8*)(kr + kb*512);
            f32x4 sA = __builtin_amdgcn_mfma_f32_16x16x32_bf16(kfrag, qhi0, zero4, 0, 0, 0);
            sA = __builtin_amdgcn_mfma_f32_16x16x32_bf16(kfrag, qlo0, sA, 0, 0, 0);
            float a0 = __builtin_amdgcn_exp2f(sA.x);
            float a1 = __builtin_amdgcn_exp2f(sA.y);
            float a2 = __builtin_amdgcn_exp2f(sA.z);
            float a3 = __builtin_amdgcn_exp2f(sA.w);
            lacc0.x += a0; lacc0.y += a1; lacc0.z += a2; lacc0.w += a3;
            unsigned int alo = cvt_pk_bf16(a0, a1);
            unsigned int ahi = cvt_pk_bf16(a2, a3);
            f32x4 sB = __builtin_amdgcn_mfma_f32_16x16x32_bf16(kfrag, qhi1, zero4, 0, 0, 0);
            sB = __builtin_amdgcn_mfma_f32_16x16x32_bf16(kfrag, qlo1, sB, 0, 0, 0);
            float b0 = __builtin_amdgcn_exp2f(sB.x);
            float b1 = __builtin_amdgcn_exp2f(sB.y);
            float b2 = __builtin_amdgcn_exp2f(sB.z);
            float b3 = __builtin_amdgcn_exp2f(sB.w);
            lacc1.x += b0; lacc1.y += b1; lacc1.z += b2; lacc1.w += b3;
            unsigned int blo = cvt_pk_bf16(b0, b1);
            unsigned int bhi = cvt_pk_bf16(b2, b3);

            if ((kb & 1) == 0) { pe00 = alo; pe01 = ahi; pe10 = blo; pe11 = bhi; }
            else {
                uint2v vE = *(const uint2v*)(vr + (kb-1)*16);
                uint2v vO = *(const uint2v*)(vr + kb*16);
                union { unsigned int uu[4]; bf16x8 h; } pa, vv;
                vv.uu[0] = vE.x; vv.uu[1] = vE.y; vv.uu[2] = vO.x; vv.uu[3] = vO.y;
                pa.uu[0] = pe00; pa.uu[1] = pe01; pa.uu[2] = alo; pa.uu[3] = ahi;
                oacc0 = __builtin_amdgcn_mfma_f32_16x16x32_bf16(pa.h, vv.h, oacc0, 0, 0, 0);
                pa.uu[0] = pe10; pa.uu[1] = pe11; pa.uu[2] = blo; pa.uu[3] = bhi;
                oacc1 = __builtin_amdgcn_mfma_f32_16x16x32_bf16(pa.h, vv.h, oacc1, 0, 0, 0);
            }
        }

        if (t + 1 < NTS) {
            int nb = (t + 1) & 1;
            *(bf16x8*)(&Ks[s][nb][0] + r0*32 + s0) = k0b;
            *(bf16x8*)(&Ks[s][nb][0] + r1*32 + s1) = k1b;
            *(bf16x8*)(&Vs[s][nb][0] + vd*72 + vseg*8) = vb_;
            k0b = k0c; k1b = k1c; vb_ = vc_;
        }
    }

    float l0 = (lacc0.x + lacc0.y) + (lacc0.z + lacc0.w);
    l0 += __shfl_xor(l0, 16);
    l0 += __shfl_xor(l0, 32);
    float l1 = (lacc1.x + lacc1.y) + (lacc1.z + lacc1.w);
    l1 += __shfl_xor(l1, 16);
    l1 += __shfl_xor(l1, 32);

    __syncthreads();
    float* mrgF = (float*)&Ks[0][0][0];
    if (s > 0) {
        float* m0 = mrgF + (((((s-1)*2 + u)*2 + 0)*64 + lane)*5);
        m0[0] = oacc0.x; m0[1] = oacc0.y; m0[2] = oacc0.z; m0[3] = oacc0.w; m0[4] = l0;
        float* m1 = mrgF + (((((s-1)*2 + u)*2 + 1)*64 + lane)*5);
        m1[0] = oacc1.x; m1[1] = oacc1.y; m1[2] = oacc1.z; m1[3] = oacc1.w; m1[4] = l1;
    }
    __syncthreads();
    if (s == 0) {
        #pragma unroll
        for (int sp = 0; sp < 3; ++sp) {
            const float* m0 = mrgF + ((((sp*2 + u)*2 + 0)*64 + lane)*5);
            oacc0.x += m0[0]; oacc0.y += m0[1]; oacc0.z += m0[2]; oacc0.w += m0[3];
            l0 += m0[4];
            const float* m1 = mrgF + ((((sp*2 + u)*2 + 1)*64 + lane)*5);
            oacc1.x += m1[0]; oacc1.y += m1[1]; oacc1.z += m1[2]; oacc1.w += m1[3];
            l1 += m1[4];
        }
        int b = bh >> 2, h = bh & 3;
        float* Ob0 = O + ((size_t)b*HW + q0 + (u*2 + 0)*16)*NC + h*DH;
        float* Ob1 = O + ((size_t)b*HW + q0 + (u*2 + 1)*16)*NC + h*DH;
        #pragma unroll
        for (int r = 0; r < 4; ++r) {
            float lr0 = __shfl(l0, 4*g + r);
            float ov0 = (r==0? oacc0.x : r==1? oacc0.y : r==2? oacc0.z : oacc0.w);
            Ob0[(4*g + r)*NC + qc] = ov0 / lr0;
            float lr1 = __shfl(l1, 4*g + r);
            float ov1 = (r==0? oacc1.x : r==1? oacc1.y : r==2? oacc1.z : oacc1.w);
            Ob1[(4*g + r)*NC + qc] = ov1 / lr1;
        }
    }
}

// ---------------------------------------------------------------------------
// Kernel C: proj 1x1 conv + transpose (round-12 verbatim).
// ---------------------------------------------------------------------------
__global__ __launch_bounds__(256) void proj_kernel(
    const float* __restrict__ O, const float* __restrict__ proj_w,
    const float* __restrict__ proj_b, float* __restrict__ y)
{
    const int PIX = 8;
    __shared__ float os[PIX][NC];
    __shared__ float ys[NC][PIX+1];
    int blk = blockIdx.x;                // 1024
    int b   = blk >> 9;
    int p0  = (blk & 511) * PIX;
    int tid = threadIdx.x;
    int c   = tid & 63;
    int pg  = tid >> 6;

    if (tid < PIX*NC/4) {
        int pp = tid >> 4, c4 = tid & 15;
        ((float4*)os[pp])[c4] = ((const float4*)(O + ((size_t)(b*HW + p0 + pp))*NC))[c4];
    }
    float wv[NC];
    #pragma unroll
    for (int c4 = 0; c4 < NC/4; c4++) {
        float4 t = ((const float4*)(proj_w + (size_t)c*NC))[c4];
        wv[4*c4+0] = t.x; wv[4*c4+1] = t.y; wv[4*c4+2] = t.z; wv[4*c4+3] = t.w;
    }
    float bias = proj_b[c];
    __syncthreads();

    #pragma unroll
    for (int u = 0; u < 2; ++u) {
        int pi = pg*2 + u;
        float a0 = 0.f, a1 = 0.f, a2 = 0.f, a3 = 0.f;
        #pragma unroll
        for (int c4 = 0; c4 < NC/4; c4++) {
            float4 ov = ((const float4*)os[pi])[c4];
            a0 = fmaf(wv[4*c4+0], ov.x, a0);
            a1 = fmaf(wv[4*c4+1], ov.y, a1);
            a2 = fmaf(wv[4*c4+2], ov.z, a2);
            a3 = fmaf(wv[4*c4+3], ov.w, a3);
        }
        ys[c][pi] = bias + ((a0 + a1) + (a2 + a3));
    }
    __syncthreads();
    for (int idx = tid; idx < PIX*NC; idx += 256) {
        int cc = idx >> 3;
        int i  = idx & 7;
        y[(size_t)(b*NC + cc)*HW + p0 + i] = ys[cc][i];
    }
}

// ---------------------------------------------------------------------------
extern "C" void kernel_launch(void* const* d_in, const int* in_sizes, int n_in,
                              void* d_out, int out_size, void* d_ws, size_t ws_size,
                              hipStream_t stream)
{
    const float* x      = (const float*)d_in[0];
    const float* illu   = (const float*)d_in[1];
    const float* qkv_w  = (const float*)d_in[2];
    const float* qkv_b  = (const float*)d_in[3];
    const float* illu_w = (const float*)d_in[4];
    const float* illu_b = (const float*)d_in[5];
    const float* proj_w = (const float*)d_in[6];
    const float* proj_b = (const float*)d_in[7];
    float* out = (float*)d_out;

    ushort* Qx   = (ushort*)d_ws;                     // 2MB (hi|lo)
    ushort* Kx   = Qx + (size_t)NBH*HW*32;            // 2MB (hi|lo)
    ushort* Vt   = Kx + (size_t)NBH*HW*32;            // 1MB [bh][d][key]
    float*  O    = (float*)(Vt + (size_t)NBH*HW*DH);  // 2MB fp32 [b][p][64]
    ushort* Wt   = (ushort*)(O + (size_t)NB*HW*NC);   // 96KB
    float*  Bias = (float*)(Wt + 49152);              // 768B

    hipLaunchKernelGGL(wprep_kernel, dim3(193), dim3(256), 0, stream,
                       qkv_w, qkv_b, illu_w, illu_b, Wt, Bias);
    hipLaunchKernelGGL(qkv_kernel, dim3(512), dim3(256), 0, stream,
                       x, illu, Wt, Bias, Qx, Kx, Vt);
    hipLaunchKernelGGL(attn_kernel, dim3(512), dim3(512), 0, stream,
                       Qx, Kx, Vt, O);
    hipLaunchKernelGGL(proj_kernel, dim3(1024), dim3(256), 0, stream,
                       O, proj_w, proj_b, out);
}

// Round 14
// 48.182 us; speedup vs baseline: 1.4351x; 1.1398x over previous
//
#include <hip/hip_runtime.h>
#include <hip/hip_bf16.h>
#include <math.h>

#define HW   4096
#define NC   64
#define NB   2
#define NHD  4
#define DH   16
#define NBH  (NB*NHD)

typedef __attribute__((ext_vector_type(4))) float f32x4;
typedef __attribute__((ext_vector_type(8))) short bf16x8;
typedef __attribute__((ext_vector_type(2))) unsigned int uint2v;

#define QSCALE 0.36067376022224087f   // 0.25 * log2(e)

static __device__ __forceinline__ unsigned short bf16_bits(float f) {
    union { __hip_bfloat16 h; unsigned short u; } cv;
    cv.h = __float2bfloat16(f);
    return cv.u;
}
static __device__ __forceinline__ float bits_to_f(unsigned short b) {
    return __uint_as_float(((unsigned int)b) << 16);
}
static __device__ __forceinline__ unsigned int cvt_pk_bf16(float lo, float hi) {
    unsigned int r;
    asm("v_cvt_pk_bf16_f32 %0, %1, %2" : "=v"(r) : "v"(lo), "v"(hi));
    return r;
}

// ---------------------------------------------------------------------------
// Kernel W: weight prep for qkv AND proj MFMA GEMMs.
// Wt  [12 ot][8 ct][2 hl][16 n][16 k8]  (z = [x;f] 128-in trick, QSCALE folded)
// Bias[192]
// Wp  [4 ot][4 ct][2 hl][16 n][16 k8]   (proj weights, hi|lo)
// ---------------------------------------------------------------------------
__global__ __launch_bounds__(256) void wprep_kernel(
    const float* __restrict__ qkv_w, const float* __restrict__ qkv_b,
    const float* __restrict__ illu_w, const float* __restrict__ illu_b,
    const float* __restrict__ proj_w,
    ushort* __restrict__ Wt, float* __restrict__ Bias, ushort* __restrict__ Wp)
{
    int idx = blockIdx.x * 256 + threadIdx.x;
    if (idx < 49152) {
        int k8 = idx & 15;
        int n  = (idx >> 4) & 15;
        int hl = (idx >> 8) & 1;
        int ct = (idx >> 9) & 7;
        int ot = idx >> 12;              // 0..11
        int c   = ct*16 + k8;            // 0..127
        int out = ot*16 + n;             // 0..191
        float w;
        if (ot < 4)       w = (c < 64) ? qkv_w[out*64 + c] * QSCALE : 0.f;
        else if (ot < 8)  w = (c < 64) ? qkv_w[out*64 + c]
                                       : illu_w[(out-64)*64 + (c-64)];
        else              w = (c < 64) ? qkv_w[out*64 + c] : 0.f;
        unsigned short hb = bf16_bits(w);
        Wt[idx] = (hl == 0) ? hb : bf16_bits(w - bits_to_f(hb));
    } else if (idx < 49344) {
        int out = idx - 49152;
        float bv = (out < 64)  ? qkv_b[out] * QSCALE
                 : (out < 128) ? qkv_b[out] + illu_b[out-64]
                 :               qkv_b[out];
        Bias[out] = bv;
    } else if (idx < 49344 + 8192) {
        int local = idx - 49344;
        int k8 = local & 15;
        int n  = (local >> 4) & 15;
        int hl = (local >> 8) & 1;
        int ct = (local >> 9) & 3;
        int ot = local >> 11;            // 0..3
        float w = proj_w[(ot*16 + n)*64 + ct*16 + k8];
        unsigned short hb = bf16_bits(w);
        Wp[local] = (hl == 0) ? hb : bf16_bits(w - bits_to_f(hb));
    }
}

// ---------------------------------------------------------------------------
// Kernel A: qkv+illu as double-bf16 MFMA GEMM (round-13 verbatim).
// ---------------------------------------------------------------------------
__global__ __launch_bounds__(256) void qkv_kernel(
    const float* __restrict__ x, const float* __restrict__ illu,
    const ushort* __restrict__ Wt, const float* __restrict__ Bias,
    ushort* __restrict__ Qx, ushort* __restrict__ Kx, ushort* __restrict__ Vt)
{
    __shared__ alignas(16) float  xf[128*20];    // [z-row 128][16 px + 4 pad]
    __shared__ alignas(16) ushort frag[8*16*32]; // [ct][px][32 slots swz]

    int blk = blockIdx.x;                // 512
    int b   = blk & 1;
    int px0 = (blk >> 1) * 16;
    int tid = threadIdx.x;
    int w   = tid >> 6;
    int lane = tid & 63;
    int g   = lane >> 4;
    int n   = lane & 15;

    #pragma unroll
    for (int rep = 0; rep < 2; ++rep) {
        int id  = tid + rep*256;
        int row = id >> 2, seg = id & 3;
        const float* src = (row < 64) ? x    + (size_t)(b*NC + row)*HW
                                      : illu + (size_t)(b*NC + row - 64)*HW;
        float4 v = *(const float4*)(src + px0 + seg*4);
        *(float4*)(xf + row*20 + seg*4) = v;
    }
    __syncthreads();

    if (tid < 128) {
        int ct = tid >> 4, px = tid & 15;
        int swz = (px & 3) ^ ((px >> 2) & 3);
        union { ushort us[8]; bf16x8 v; } g0, g1, g2, g3;
        #pragma unroll
        for (int i = 0; i < 8; ++i) {
            float v  = xf[(ct*16 + i)*20 + px];
            unsigned short hb = bf16_bits(v);
            g0.us[i] = hb;
            g2.us[i] = bf16_bits(v - bits_to_f(hb));
            float v2 = xf[(ct*16 + 8 + i)*20 + px];
            unsigned short hb2 = bf16_bits(v2);
            g1.us[i] = hb2;
            g3.us[i] = bf16_bits(v2 - bits_to_f(hb2));
        }
        ushort* fb = frag + (ct*16 + px)*32;
        *(bf16x8*)(fb + ((0 ^ swz)*8)) = g0.v;
        *(bf16x8*)(fb + ((1 ^ swz)*8)) = g1.v;
        *(bf16x8*)(fb + ((2 ^ swz)*8)) = g2.v;
        *(bf16x8*)(fb + ((3 ^ swz)*8)) = g3.v;
    }
    __syncthreads();

    f32x4 zero4 = {0.f, 0.f, 0.f, 0.f};
    int px  = n;
    int swz = (px & 3) ^ ((px >> 2) & 3);
    const ushort* af_base = frag + px*32 + (g ^ swz)*8;

    #pragma unroll
    for (int j = 0; j < 3; ++j) {
        int ot  = w + 4*j;                // 0..11
        int nct = (ot >= 4 && ot < 8) ? 8 : 4;
        f32x4 acc = zero4;
        for (int ct = 0; ct < nct; ++ct) {
            bf16x8 af = *(const bf16x8*)(af_base + ct*512);
            const ushort* wb = Wt + ((size_t)(ot*8 + ct)*2)*256 + n*16 + (g&1)*8;
            bf16x8 bh = *(const bf16x8*)(wb);
            bf16x8 bl = *(const bf16x8*)(wb + 256);
            acc = __builtin_amdgcn_mfma_f32_16x16x32_bf16(af, bh, acc, 0, 0, 0);
            acc = __builtin_amdgcn_mfma_f32_16x16x32_bf16(af, bl, acc, 0, 0, 0);
        }
        float bias = Bias[ot*16 + n];
        float v0 = acc.x + bias, v1 = acc.y + bias;
        float v2 = acc.z + bias, v3 = acc.w + bias;
        if (ot < 8) {
            ushort* dst = (ot < 4) ? Qx : Kx;
            int head = ot & 3;
            size_t base = ((size_t)(b*NHD + head))*HW*32;
            #pragma unroll
            for (int r = 0; r < 4; ++r) {
                float val = (r==0? v0 : r==1? v1 : r==2? v2 : v3);
                int pxr = px0 + 4*g + r;
                unsigned short hb = bf16_bits(val);
                dst[base + (size_t)pxr*32 + n]      = hb;
                dst[base + (size_t)pxr*32 + 16 + n] = bf16_bits(val - bits_to_f(hb));
            }
        } else {
            int co = (ot - 8)*16 + n;
            uint2v pk;
            pk.x = cvt_pk_bf16(v0, v1);
            pk.y = cvt_pk_bf16(v2, v3);
            *(uint2v*)(Vt + ((size_t)(b*NC + co))*HW + px0 + 4*g) = pk;
        }
    }
}

// ---------------------------------------------------------------------------
// Kernel B: MFMA flash attention (round-12/13 verbatim).
// ---------------------------------------------------------------------------
#define KT   64
#define SPL  4
#define KPS  1024
#define NTS  (KPS/KT)

__global__ __launch_bounds__(512) void attn_kernel(
    const ushort* __restrict__ Qx, const ushort* __restrict__ Kx,
    const ushort* __restrict__ Vt, float* __restrict__ O)
{
    __shared__ alignas(16) ushort Ks[SPL][2][64*32];
    __shared__ alignas(16) ushort Vs[SPL][2][16*72];

    int blk  = blockIdx.x;               // 512
    int bh   = blk & 7;
    int q0   = (blk >> 3) * 64;
    int tid  = threadIdx.x;
    int w    = tid >> 6;
    int s    = w >> 1;
    int u    = w & 1;
    int lane = tid & 63;
    int g    = lane >> 4;
    int qc   = lane & 15;

    const ushort* Qb = Qx + (size_t)bh*HW*32;
    const ushort* Kb = Kx + (size_t)bh*HW*32 + (size_t)s*KPS*32;
    const ushort* Vb = Vt + (size_t)bh*DH*HW;

    int qrow0 = q0 + (u*2 + 0)*16 + qc;
    int qrow1 = q0 + (u*2 + 1)*16 + qc;
    bf16x8 qhi0 = *(const bf16x8*)(Qb + (size_t)qrow0*32 +      8*(g&1));
    bf16x8 qlo0 = *(const bf16x8*)(Qb + (size_t)qrow0*32 + 16 + 8*(g&1));
    bf16x8 qhi1 = *(const bf16x8*)(Qb + (size_t)qrow1*32 +      8*(g&1));
    bf16x8 qlo1 = *(const bf16x8*)(Qb + (size_t)qrow1*32 + 16 + 8*(g&1));

    f32x4 zero4 = {0.f, 0.f, 0.f, 0.f};
    f32x4 oacc0 = zero4, oacc1 = zero4;
    f32x4 lacc0 = zero4, lacc1 = zero4;

    int mconst = (qc & 3) ^ ((qc >> 2) & 3);
    const int koff = qc*32 + ((g ^ mconst)*8);
    const int voff = qc*72 + 4*g;

    int gt = tid & 127;
    int f0 = gt,        r0 = f0 >> 2, h0 = f0 & 3;
    int f1 = gt + 128,  r1 = f1 >> 2, h1 = f1 & 3;
    int s0 = (h0 ^ ((r0 & 3) ^ ((r0 >> 2) & 3))) * 8;
    int s1 = (h1 ^ ((r1 & 3) ^ ((r1 >> 2) & 3))) * 8;
    int vd = gt >> 3, vseg = gt & 7;

    {
        bf16x8 a0 = *(const bf16x8*)(Kb + (size_t)r0*32 + 8*h0);
        bf16x8 a1 = *(const bf16x8*)(Kb + (size_t)r1*32 + 8*h1);
        bf16x8 av = *(const bf16x8*)(Vb + (size_t)vd*HW + s*KPS + vseg*8);
        *(bf16x8*)(&Ks[s][0][0] + r0*32 + s0) = a0;
        *(bf16x8*)(&Ks[s][0][0] + r1*32 + s1) = a1;
        *(bf16x8*)(&Vs[s][0][0] + vd*72 + vseg*8) = av;
    }
    bf16x8 k0b = *(const bf16x8*)(Kb + (size_t)(KT + r0)*32 + 8*h0);
    bf16x8 k1b = *(const bf16x8*)(Kb + (size_t)(KT + r1)*32 + 8*h1);
    bf16x8 vb_ = *(const bf16x8*)(Vb + (size_t)vd*HW + s*KPS + KT + vseg*8);

    for (int t = 0; t < NTS; ++t) {
        __syncthreads();
        bf16x8 k0c = k0b, k1c = k1b, vc_ = vb_;
        if (t + 2 < NTS) {
            int kt = (t + 2) * KT;
            k0c = *(const bf16x8*)(Kb + (size_t)(kt + r0)*32 + 8*h0);
            k1c = *(const bf16x8*)(Kb + (size_t)(kt + r1)*32 + 8*h1);
            vc_ = *(const bf16x8*)(Vb + (size_t)vd*HW + s*KPS + kt + vseg*8);
        }

        const ushort* kr = &Ks[s][t & 1][0] + koff;
        const ushort* vr = &Vs[s][t & 1][0] + voff;
        unsigned int pe00 = 0, pe01 = 0, pe10 = 0, pe11 = 0;
        #pragma unroll
        for (int kb = 0; kb < 4; ++kb) {
            bf16x8 kfrag = *(const bf16x8*)(kr + kb*512);
            f32x4 sA = __builtin_amdgcn_mfma_f32_16x16x32_bf16(kfrag, qhi0, zero4, 0, 0, 0);
            sA = __builtin_amdgcn_mfma_f32_16x16x32_bf16(kfrag, qlo0, sA, 0, 0, 0);
            float a0 = __builtin_amdgcn_exp2f(sA.x);
            float a1 = __builtin_amdgcn_exp2f(sA.y);
            float a2 = __builtin_amdgcn_exp2f(sA.z);
            float a3 = __builtin_amdgcn_exp2f(sA.w);
            lacc0.x += a0; lacc0.y += a1; lacc0.z += a2; lacc0.w += a3;
            unsigned int alo = cvt_pk_bf16(a0, a1);
            unsigned int ahi = cvt_pk_bf16(a2, a3);
            f32x4 sB = __builtin_amdgcn_mfma_f32_16x16x32_bf16(kfrag, qhi1, zero4, 0, 0, 0);
            sB = __builtin_amdgcn_mfma_f32_16x16x32_bf16(kfrag, qlo1, sB, 0, 0, 0);
            float b0 = __builtin_amdgcn_exp2f(sB.x);
            float b1 = __builtin_amdgcn_exp2f(sB.y);
            float b2 = __builtin_amdgcn_exp2f(sB.z);
            float b3 = __builtin_amdgcn_exp2f(sB.w);
            lacc1.x += b0; lacc1.y += b1; lacc1.z += b2; lacc1.w += b3;
            unsigned int blo = cvt_pk_bf16(b0, b1);
            unsigned int bhi = cvt_pk_bf16(b2, b3);

            if ((kb & 1) == 0) { pe00 = alo; pe01 = ahi; pe10 = blo; pe11 = bhi; }
            else {
                uint2v vE = *(const uint2v*)(vr + (kb-1)*16);
                uint2v vO = *(const uint2v*)(vr + kb*16);
                union { unsigned int uu[4]; bf16x8 h; } pa, vv;
                vv.uu[0] = vE.x; vv.uu[1] = vE.y; vv.uu[2] = vO.x; vv.uu[3] = vO.y;
                pa.uu[0] = pe00; pa.uu[1] = pe01; pa.uu[2] = alo; pa.uu[3] = ahi;
                oacc0 = __builtin_amdgcn_mfma_f32_16x16x32_bf16(pa.h, vv.h, oacc0, 0, 0, 0);
                pa.uu[0] = pe10; pa.uu[1] = pe11; pa.uu[2] = blo; pa.uu[3] = bhi;
                oacc1 = __builtin_amdgcn_mfma_f32_16x16x32_bf16(pa.h, vv.h, oacc1, 0, 0, 0);
            }
        }

        if (t + 1 < NTS) {
            int nb = (t + 1) & 1;
            *(bf16x8*)(&Ks[s][nb][0] + r0*32 + s0) = k0b;
            *(bf16x8*)(&Ks[s][nb][0] + r1*32 + s1) = k1b;
            *(bf16x8*)(&Vs[s][nb][0] + vd*72 + vseg*8) = vb_;
            k0b = k0c; k1b = k1c; vb_ = vc_;
        }
    }

    float l0 = (lacc0.x + lacc0.y) + (lacc0.z + lacc0.w);
    l0 += __shfl_xor(l0, 16);
    l0 += __shfl_xor(l0, 32);
    float l1 = (lacc1.x + lacc1.y) + (lacc1.z + lacc1.w);
    l1 += __shfl_xor(l1, 16);
    l1 += __shfl_xor(l1, 32);

    __syncthreads();
    float* mrgF = (float*)&Ks[0][0][0];
    if (s > 0) {
        float* m0 = mrgF + (((((s-1)*2 + u)*2 + 0)*64 + lane)*5);
        m0[0] = oacc0.x; m0[1] = oacc0.y; m0[2] = oacc0.z; m0[3] = oacc0.w; m0[4] = l0;
        float* m1 = mrgF + (((((s-1)*2 + u)*2 + 1)*64 + lane)*5);
        m1[0] = oacc1.x; m1[1] = oacc1.y; m1[2] = oacc1.z; m1[3] = oacc1.w; m1[4] = l1;
    }
    __syncthreads();
    if (s == 0) {
        #pragma unroll
        for (int sp = 0; sp < 3; ++sp) {
            const float* m0 = mrgF + ((((sp*2 + u)*2 + 0)*64 + lane)*5);
            oacc0.x += m0[0]; oacc0.y += m0[1]; oacc0.z += m0[2]; oacc0.w += m0[3];
            l0 += m0[4];
            const float* m1 = mrgF + ((((sp*2 + u)*2 + 1)*64 + lane)*5);
            oacc1.x += m1[0]; oacc1.y += m1[1]; oacc1.z += m1[2]; oacc1.w += m1[3];
            l1 += m1[4];
        }
        int b = bh >> 2, h = bh & 3;
        float* Ob0 = O + ((size_t)b*HW + q0 + (u*2 + 0)*16)*NC + h*DH;
        float* Ob1 = O + ((size_t)b*HW + q0 + (u*2 + 1)*16)*NC + h*DH;
        #pragma unroll
        for (int r = 0; r < 4; ++r) {
            float lr0 = __shfl(l0, 4*g + r);
            float ov0 = (r==0? oacc0.x : r==1? oacc0.y : r==2? oacc0.z : oacc0.w);
            Ob0[(4*g + r)*NC + qc] = ov0 / lr0;
            float lr1 = __shfl(l1, 4*g + r);
            float ov1 = (r==0? oacc1.x : r==1? oacc1.y : r==2? oacc1.z : oacc1.w);
            Ob1[(4*g + r)*NC + qc] = ov1 / lr1;
        }
    }
}

// ---------------------------------------------------------------------------
// Kernel C: proj as double-bf16 MFMA GEMM. 512 blocks x 256 thr (4 waves),
// 16 px/block. Stage O [px][64] -> of[c][px] -> hi/lo A-frags (qkv's granule
// code); wave w computes out-tile w (4 ct x 2 MFMAs); +bias -> ys[c][px] ->
// coalesced float4 writes to y [b][c][p].
// ---------------------------------------------------------------------------
__global__ __launch_bounds__(256) void proj_kernel(
    const float* __restrict__ O, const ushort* __restrict__ Wp,
    const float* __restrict__ proj_b, float* __restrict__ y)
{
    __shared__ alignas(16) float  of[64*20];     // [c][16 px + 4 pad]
    __shared__ alignas(16) ushort frag[4*16*32]; // [ct][px][32 swz]
    __shared__ alignas(16) float  ys[64][20];    // [c][px]

    int blk = blockIdx.x;                // 512
    int b   = blk & 1;
    int px0 = (blk >> 1) * 16;
    int tid = threadIdx.x;
    int w   = tid >> 6;
    int lane = tid & 63;
    int g   = lane >> 4;
    int n   = lane & 15;

    // stage 1: O [px][64] fp32 -> of[c][px] (coalesced read, LDS transpose)
    {
        int px = tid >> 4, c4 = tid & 15;
        float4 v = *(const float4*)(O + ((size_t)(b*HW + px0 + px))*NC + c4*4);
        of[(c4*4+0)*20 + px] = v.x;
        of[(c4*4+1)*20 + px] = v.y;
        of[(c4*4+2)*20 + px] = v.z;
        of[(c4*4+3)*20 + px] = v.w;
    }
    __syncthreads();

    // stage 2: hi/lo bf16 granules (64 threads)
    if (tid < 64) {
        int ct = tid >> 4, px = tid & 15;
        int swz = (px & 3) ^ ((px >> 2) & 3);
        union { ushort us[8]; bf16x8 v; } g0, g1, g2, g3;
        #pragma unroll
        for (int i = 0; i < 8; ++i) {
            float v  = of[(ct*16 + i)*20 + px];
            unsigned short hb = bf16_bits(v);
            g0.us[i] = hb;
            g2.us[i] = bf16_bits(v - bits_to_f(hb));
            float v2 = of[(ct*16 + 8 + i)*20 + px];
            unsigned short hb2 = bf16_bits(v2);
            g1.us[i] = hb2;
            g3.us[i] = bf16_bits(v2 - bits_to_f(hb2));
        }
        ushort* fb = frag + (ct*16 + px)*32;
        *(bf16x8*)(fb + ((0 ^ swz)*8)) = g0.v;
        *(bf16x8*)(fb + ((1 ^ swz)*8)) = g1.v;
        *(bf16x8*)(fb + ((2 ^ swz)*8)) = g2.v;
        *(bf16x8*)(fb + ((3 ^ swz)*8)) = g3.v;
    }
    __syncthreads();

    // GEMM: wave w -> out-tile w (16 out ch), 4 ct x 2 MFMAs
    f32x4 acc = {0.f, 0.f, 0.f, 0.f};
    int px  = n;
    int swz = (px & 3) ^ ((px >> 2) & 3);
    const ushort* af_base = frag + px*32 + (g ^ swz)*8;
    #pragma unroll
    for (int ct = 0; ct < 4; ++ct) {
        bf16x8 af = *(const bf16x8*)(af_base + ct*512);
        const ushort* wb = Wp + ((size_t)(w*4 + ct)*2)*256 + n*16 + (g&1)*8;
        bf16x8 bh = *(const bf16x8*)(wb);
        bf16x8 bl = *(const bf16x8*)(wb + 256);
        acc = __builtin_amdgcn_mfma_f32_16x16x32_bf16(af, bh, acc, 0, 0, 0);
        acc = __builtin_amdgcn_mfma_f32_16x16x32_bf16(af, bl, acc, 0, 0, 0);
    }
    float bias = proj_b[w*16 + n];
    ys[w*16 + n][4*g+0] = acc.x + bias;    // C[px=4g+r][out=n] -> ys[c][px]
    ys[w*16 + n][4*g+1] = acc.y + bias;
    ys[w*16 + n][4*g+2] = acc.z + bias;
    ys[w*16 + n][4*g+3] = acc.w + bias;
    __syncthreads();

    // coalesced output: 64 rows x 4 float4 each
    {
        int row = tid >> 2, seg = tid & 3;
        float4 v;
        v.x = ys[row][seg*4+0]; v.y = ys[row][seg*4+1];
        v.z = ys[row][seg*4+2]; v.w = ys[row][seg*4+3];
        *(float4*)(y + ((size_t)(b*NC + row))*HW + px0 + seg*4) = v;
    }
}

// ---------------------------------------------------------------------------
extern "C" void kernel_launch(void* const* d_in, const int* in_sizes, int n_in,
                              void* d_out, int out_size, void* d_ws, size_t ws_size,
                              hipStream_t stream)
{
    const float* x      = (const float*)d_in[0];
    const float* illu   = (const float*)d_in[1];
    const float* qkv_w  = (const float*)d_in[2];
    const float* qkv_b  = (const float*)d_in[3];
    const float* illu_w = (const float*)d_in[4];
    const float* illu_b = (const float*)d_in[5];
    const float* proj_w = (const float*)d_in[6];
    const float* proj_b = (const float*)d_in[7];
    float* out = (float*)d_out;

    ushort* Qx   = (ushort*)d_ws;                     // 2MB (hi|lo)
    ushort* Kx   = Qx + (size_t)NBH*HW*32;            // 2MB (hi|lo)
    ushort* Vt   = Kx + (size_t)NBH*HW*32;            // 1MB [bh][d][key]
    float*  O    = (float*)(Vt + (size_t)NBH*HW*DH);  // 2MB fp32 [b][p][64]
    ushort* Wt   = (ushort*)(O + (size_t)NB*HW*NC);   // 96KB
    float*  Bias = (float*)(Wt + 49152);              // 768B
    ushort* Wp   = (ushort*)(Bias + 192);             // 16KB

    hipLaunchKernelGGL(wprep_kernel, dim3(225), dim3(256), 0, stream,
                       qkv_w, qkv_b, illu_w, illu_b, proj_w, Wt, Bias, Wp);
    hipLaunchKernelGGL(qkv_kernel, dim3(512), dim3(256), 0, stream,
                       x, illu, Wt, Bias, Qx, Kx, Vt);
    hipLaunchKernelGGL(attn_kernel, dim3(512), dim3(512), 0, stream,
                       Qx, Kx, Vt, O);
    hipLaunchKernelGGL(proj_kernel, dim3(512), dim3(256), 0, stream,
                       O, Wp, proj_b, out);
}